// Round 2
// baseline (723.126 us; speedup 1.0000x reference)
//
#include <hip/hip_runtime.h>

typedef unsigned short u16;
typedef unsigned int u32;
typedef __attribute__((ext_vector_type(8))) short sv8;   // 8 x bf16 (4 VGPR)
typedef __attribute__((ext_vector_type(4))) float fv4;   // MFMA accumulator

__device__ __forceinline__ u16 f2b(float f) {
  u32 u = __builtin_bit_cast(u32, f);
  u32 r = (u + 0x7fffu + ((u >> 16) & 1u)) >> 16;
  return (u16)r;
}
__device__ __forceinline__ float b2f(u16 h) {
  return __builtin_bit_cast(float, ((u32)h) << 16);
}
__device__ __forceinline__ void gld16(const void* g, void* l) {
  __builtin_amdgcn_global_load_lds(
      (const __attribute__((address_space(1))) u32*)g,
      (__attribute__((address_space(3))) u32*)l, 16, 0, 0);
}

// ---------------- cast f32 -> bf16 ----------------
__global__ __launch_bounds__(256) void cast_k(const float4* __restrict__ in,
                                              u16* __restrict__ out, int n4) {
  int i = blockIdx.x * 256 + threadIdx.x;
  const int stride = gridDim.x * 256;
  for (; i < n4; i += stride) {
    float4 v = in[i];
    u32 p0 = (u32)f2b(v.x) | ((u32)f2b(v.y) << 16);
    u32 p1 = (u32)f2b(v.z) | ((u32)f2b(v.w) << 16);
    uint2 o; o.x = p0; o.y = p1;
    ((uint2*)out)[i] = o;
  }
}

// ---------------- weight transpose + cast:  Wt[e][d] = W[d][e] ----------------
__global__ __launch_bounds__(256) void wtrans_k(const float* __restrict__ W0,
                                                const float* __restrict__ W1,
                                                const float* __restrict__ W2,
                                                const float* __restrict__ W3,
                                                u16* __restrict__ out) {
  const int z = blockIdx.z;
  const float* W = (z == 0) ? W0 : (z == 1) ? W1 : (z == 2) ? W2 : W3;
  u16* o = out + (size_t)z * 1048576;
  __shared__ float t[32][33];
  const int tid = threadIdx.x;
  const int r = tid >> 5, cc = tid & 31;
  const int d0 = blockIdx.x * 32, e0 = blockIdx.y * 32;
#pragma unroll
  for (int i = 0; i < 4; ++i)
    t[r + i * 8][cc] = W[(size_t)(d0 + r + i * 8) * 1024 + e0 + cc];
  __syncthreads();
#pragma unroll
  for (int i = 0; i < 4; ++i) {
    int row = r + i * 8;
    o[(size_t)(e0 + row) * 1024 + d0 + cc] = f2b(t[cc][row]);
  }
}

// ---------------- m97-style GEMM: C[M,1024] = A[M,1024] * Bt[1024,1024]^T ----------------
// MODE 0: out = bf16(acc + bias)          -> outb
// MODE 1: out = acc + bias + resid (f32)  -> outf
template <int MODE>
__global__ __launch_bounds__(256) void gemm_k(const u16* __restrict__ A,
                                              const u16* __restrict__ Bt,
                                              const float* __restrict__ bias,
                                              const float* __restrict__ resid,
                                              u16* __restrict__ outb,
                                              float* __restrict__ outf, int M) {
  __shared__ u16 As[128 * 32];
  __shared__ u16 Bs[128 * 32];
  const int tid = threadIdx.x;
  const int lane = tid & 63;
  const int w = tid >> 6;
  const int l15 = lane & 15, l4 = lane >> 4;
  const int bcol0 = blockIdx.x * 128;   // N fastest -> B panel stays in L2
  const int brow0 = blockIdx.y * 128;
  const int wr = (w >> 1) * 64;
  const int wc = (w & 1) * 64;
  fv4 acc[4][4] = {};

  const u32 off0 = (u32)tid * 16;
  const u32 off1 = off0 + 4096;
  const u32 r0 = off0 >> 6, c0b = off0 & 63;
  const u32 r1 = off1 >> 6, c1b = off1 & 63;
  const char* Ab = (const char*)A + (size_t)brow0 * 2048;
  const char* Bb = (const char*)Bt + (size_t)bcol0 * 2048;

  for (int k0 = 0; k0 < 1024; k0 += 32) {
    gld16(Ab + (size_t)r0 * 2048 + k0 * 2 + c0b, (char*)As + off0);
    gld16(Ab + (size_t)r1 * 2048 + k0 * 2 + c1b, (char*)As + off1);
    gld16(Bb + (size_t)r0 * 2048 + k0 * 2 + c0b, (char*)Bs + off0);
    gld16(Bb + (size_t)r1 * 2048 + k0 * 2 + c1b, (char*)Bs + off1);
    __syncthreads();
    sv8 a[4], bb[4];
#pragma unroll
    for (int m = 0; m < 4; ++m)
      a[m] = *(const sv8*)&As[(wr + m * 16 + l15) * 32 + l4 * 8];
#pragma unroll
    for (int n = 0; n < 4; ++n)
      bb[n] = *(const sv8*)&Bs[(wc + n * 16 + l15) * 32 + l4 * 8];
#pragma unroll
    for (int m = 0; m < 4; ++m)
#pragma unroll
      for (int n = 0; n < 4; ++n)
        acc[m][n] = __builtin_amdgcn_mfma_f32_16x16x32_bf16(a[m], bb[n], acc[m][n], 0, 0, 0);
    __syncthreads();
  }
#pragma unroll
  for (int n = 0; n < 4; ++n) {
    const int col = bcol0 + wc + n * 16 + l15;
    const float bv = bias[col];
#pragma unroll
    for (int m = 0; m < 4; ++m) {
      fv4 v = acc[m][n];
#pragma unroll
      for (int j = 0; j < 4; ++j) {
        const int row = brow0 + wr + m * 16 + l4 * 4 + j;
        const size_t idx = (size_t)row * 1024 + col;
        float r = v[j] + bv;
        if (MODE == 0) outb[idx] = f2b(r);
        else           outf[idx] = r + resid[idx];
      }
    }
  }
}

// ---------------- fused attention (one block per b) ----------------
// LDS map (bytes):
//  union: pass1 Xc[48][136]bf16 @0 (13056), Yc[64][136]bf16 @13056 (end 30464)
//         pass2 TcT[128][72]bf16 @0 (18432), IcT[128][72]bf16 @18432 (end 36864)
//  attL f32[48][52] @36864 ; att1b bf16[48][72] @46848 ; att2b bf16[64][72] @53760
//  wx @62976, wy @63168, rsx @63424, rsy @63616, xm @63872, ym @63912 ; total 63968
__global__ __launch_bounds__(256) void attn_k(const u16* __restrict__ Xb,
                                              const u16* __restrict__ Yb,
                                              const u16* __restrict__ imgA,
                                              const u16* __restrict__ txtA,
                                              const void* __restrict__ xmask,
                                              const void* __restrict__ ymask,
                                              u16* __restrict__ gx,
                                              u16* __restrict__ gy) {
  __shared__ __attribute__((aligned(16))) unsigned char smem[63968];
  const int b = blockIdx.x;
  const int tid = threadIdx.x;
  const int lane = tid & 63;
  const int w = tid >> 6;
  const int l15 = lane & 15, l4 = lane >> 4;

  u32* smU = (u32*)smem;
  float* attL = (float*)(smem + 36864);
  float* wxL = (float*)(smem + 62976);
  float* wyL = (float*)(smem + 63168);
  float* rsx = (float*)(smem + 63424);
  float* rsy = (float*)(smem + 63616);
  unsigned char* xm = smem + 63872;
  unsigned char* ym = smem + 63912;

  // mask dtype auto-detect: int32 0/1 data ORs to <=1; uint8 bool data ORs to
  // ~0x01010101 (misdetect prob ~2^-256). Wave-uniform result, no divergence.
  u32 det = 0;
  {
    const u32* mm = (const u32*)xmask;
#pragma unroll
    for (int i = 0; i < 16; ++i) det |= mm[i * 4];
    det |= mm[1]; det |= mm[2]; det |= mm[3];
  }
  const bool m_i32 = (det <= 1u);
  const int* xmi = (const int*)xmask;
  const int* ymi = (const int*)ymask;
  const unsigned char* xmb = (const unsigned char*)xmask;
  const unsigned char* ymb = (const unsigned char*)ymask;

  // zero pads: Xc rows 36..47, Yc rows 50..63, att1b, att2b (full)
  for (int i = tid; i < 816; i += 256) smU[2448 + i] = 0;
  for (int i = tid; i < 952; i += 256) smU[6664 + i] = 0;
  for (int i = tid; i < 1728; i += 256) smU[11712 + i] = 0;
  for (int i = tid; i < 2304; i += 256) smU[13440 + i] = 0;
  if (tid < 36) xm[tid] = (unsigned char)(m_i32 ? (xmi[b * 36 + tid] != 0)
                                                : (xmb[b * 36 + tid] != 0));
  if (tid < 50) ym[tid] = (unsigned char)(m_i32 ? (ymi[b * 50 + tid] != 0)
                                                : (ymb[b * 50 + tid] != 0));

  float npart[22];
#pragma unroll
  for (int i = 0; i < 22; ++i) npart[i] = 0.f;
  fv4 acc1[3] = {};

  const u32* XgU = (const u32*)(Xb + (size_t)b * 36 * 1024);
  const u32* YgU = (const u32*)(Yb + (size_t)b * 50 * 1024);
  __syncthreads();

  // ---- pass 1: scores (48x64 padded) + row norms, 8 chunks of 128 ----
  for (int c = 0; c < 8; ++c) {
    for (int e = tid; e < 2304; e += 256) {           // Xc: 36 rows x 64 u32
      int row = e >> 6, col = e & 63;
      smU[row * 68 + col] = XgU[row * 512 + c * 64 + col];
    }
    for (int e = tid; e < 3200; e += 256) {           // Yc: 50 rows x 64 u32
      int row = e >> 6, col = e & 63;
      smU[3264 + row * 68 + col] = YgU[row * 512 + c * 64 + col];
    }
    __syncthreads();
#pragma unroll
    for (int i = 0; i < 22; ++i) {                    // norms, lane-parallel
      int r = w + 4 * i;
      if (r < 86) {
        u32 u = (r < 36) ? smU[r * 68 + lane] : smU[3264 + (r - 36) * 68 + lane];
        float lo = __builtin_bit_cast(float, u << 16);
        float hi = __builtin_bit_cast(float, u & 0xffff0000u);
        npart[i] += lo * lo + hi * hi;
      }
    }
#pragma unroll
    for (int t = 0; t < 3; ++t) {                     // 12 tiles / 4 waves
      int q = w * 3 + t;
      int tm = q >> 2, tn = q & 3;
#pragma unroll
      for (int ks = 0; ks < 4; ++ks) {
        sv8 av = *(const sv8*)(smem + (tm * 16 + l15) * 272 + ks * 64 + l4 * 16);
        sv8 bv = *(const sv8*)(smem + 13056 + (tn * 16 + l15) * 272 + ks * 64 + l4 * 16);
        acc1[t] = __builtin_amdgcn_mfma_f32_16x16x32_bf16(av, bv, acc1[t], 0, 0, 0);
      }
    }
    __syncthreads();
  }
  // norm reduce + write
#pragma unroll
  for (int i = 0; i < 22; ++i) {
    int r = w + 4 * i;
    if (r < 86) {
      float v = npart[i];
      for (int s = 32; s > 0; s >>= 1) v += __shfl_xor(v, s);
      if (lane == 0) { if (r < 36) wxL[r] = sqrtf(v); else wyL[r - 36] = sqrtf(v); }
    }
  }
#pragma unroll
  for (int t = 0; t < 3; ++t) {
    int q = w * 3 + t; int tm = q >> 2, tn = q & 3;
    int col = tn * 16 + l15;
    if (col < 52) {
#pragma unroll
      for (int j = 0; j < 4; ++j)
        attL[(tm * 16 + l4 * 4 + j) * 52 + col] = acc1[t][j];
    }
  }
  __syncthreads();

  // ---- masked softmaxes (unnormalized exp stored, recip sums kept) ----
  if (tid < 36) {
    int n = tid;
    float rx = wxL[n];
    float mx = -3.4e38f;
    for (int m = 0; m < 50; ++m) {
      float v = attL[n * 52 + m] / fmaxf(rx * wyL[m], 1e-8f);
      float s = ym[m] ? -1e9f : v;
      mx = fmaxf(mx, s);
    }
    float sum = 0.f;
    for (int m = 0; m < 50; ++m) {
      float v = attL[n * 52 + m] / fmaxf(rx * wyL[m], 1e-8f);
      float s = ym[m] ? -1e9f : v;
      float e = __expf(s - mx);
      sum += e;
      ((u16*)(smem + 46848))[n * 72 + m] = f2b(e);
    }
    rsx[n] = 1.f / sum;
  } else if (tid >= 64 && tid < 114) {
    int m = tid - 64;
    float ry = wyL[m];
    float mx = -3.4e38f;
    for (int n = 0; n < 36; ++n) {
      float v = attL[n * 52 + m] / fmaxf(wxL[n] * ry, 1e-8f);
      float s = xm[n] ? -1e9f : v;
      mx = fmaxf(mx, s);
    }
    float sum = 0.f;
    for (int n = 0; n < 36; ++n) {
      float v = attL[n * 52 + m] / fmaxf(wxL[n] * ry, 1e-8f);
      float s = xm[n] ? -1e9f : v;
      float e = __expf(s - mx);
      sum += e;
      ((u16*)(smem + 53760))[m * 72 + n] = f2b(e);
    }
    rsy[m] = 1.f / sum;
  }
  __syncthreads();

  // zero TcT cols 48..63 (u32 24..31) and IcT cols 32..63 (u32 16..31), once
  for (int i = tid; i < 1024; i += 256) {
    int row = i >> 3, cu = i & 7;
    smU[row * 36 + 24 + cu] = 0;
  }
  for (int i = tid; i < 2048; i += 256) {
    int row = i >> 4, cu = i & 15;
    smU[4608 + row * 36 + 16 + cu] = 0;
  }
  const u32* TgU = (const u32*)(txtA + (size_t)b * 50 * 1024);
  const u32* IgU = (const u32*)(imgA + (size_t)b * 36 * 1024);
  __syncthreads();

  // ---- pass 2: P@E both directions + gating, 8 chunks of 128 ----
  for (int c = 0; c < 8; ++c) {
    for (int e = tid; e < 1600; e += 256) {           // TcT[d][m] transpose-stage
      int d2 = e & 63, m2 = e >> 6;
      u32 g0 = TgU[(2 * m2) * 512 + c * 64 + d2];
      u32 g1 = TgU[(2 * m2 + 1) * 512 + c * 64 + d2];
      smU[(2 * d2) * 36 + m2] = (g0 & 0xffffu) | ((g1 & 0xffffu) << 16);
      smU[(2 * d2 + 1) * 36 + m2] = (g0 >> 16) | (g1 & 0xffff0000u);
    }
    for (int e = tid; e < 1152; e += 256) {           // IcT[d][n]
      int d2 = e & 63, m2 = e >> 6;
      u32 g0 = IgU[(2 * m2) * 512 + c * 64 + d2];
      u32 g1 = IgU[(2 * m2 + 1) * 512 + c * 64 + d2];
      smU[4608 + (2 * d2) * 36 + m2] = (g0 & 0xffffu) | ((g1 & 0xffffu) << 16);
      smU[4608 + (2 * d2 + 1) * 36 + m2] = (g0 >> 16) | (g1 & 0xffff0000u);
    }
    __syncthreads();
#pragma unroll
    for (int i = 0; i < 14; ++i) {                    // 24 att_x + 32 att_y tiles
      int q = w * 14 + i;
      fv4 pacc = {};
      if (q < 24) {
        int tm = q >> 3, td = q & 7;
#pragma unroll
        for (int ks = 0; ks < 2; ++ks) {
          sv8 av = *(const sv8*)(smem + 46848 + (tm * 16 + l15) * 144 + ks * 64 + l4 * 16);
          sv8 bv = *(const sv8*)(smem + (td * 16 + l15) * 144 + ks * 64 + l4 * 16);
          pacc = __builtin_amdgcn_mfma_f32_16x16x32_bf16(av, bv, pacc, 0, 0, 0);
        }
        int dd = td * 16 + l15;
#pragma unroll
        for (int j = 0; j < 4; ++j) {
          int n = tm * 16 + l4 * 4 + j;
          if (n < 36) {
            float s = pacc[j] * rsx[n];
            float img = b2f(((const u16*)smem)[9216 + dd * 72 + n]);
            float g = s / (1.f + __expf(-s * img));
            gx[((size_t)(b * 36 + n)) * 1024 + c * 128 + dd] = f2b(g);
          }
        }
      } else {
        int q2 = q - 24;
        int tm = q2 >> 3, td = q2 & 7;
#pragma unroll
        for (int ks = 0; ks < 2; ++ks) {
          sv8 av = *(const sv8*)(smem + 53760 + (tm * 16 + l15) * 144 + ks * 64 + l4 * 16);
          sv8 bv = *(const sv8*)(smem + 18432 + (td * 16 + l15) * 144 + ks * 64 + l4 * 16);
          pacc = __builtin_amdgcn_mfma_f32_16x16x32_bf16(av, bv, pacc, 0, 0, 0);
        }
        int dd = td * 16 + l15;
#pragma unroll
        for (int j = 0; j < 4; ++j) {
          int m = tm * 16 + l4 * 4 + j;
          if (m < 50) {
            float s = pacc[j] * rsy[m];
            float tv = b2f(((const u16*)smem)[dd * 72 + m]);
            float g = s / (1.f + __expf(-s * tv));
            gy[((size_t)(b * 50 + m)) * 1024 + c * 128 + dd] = f2b(g);
          }
        }
      }
    }
    __syncthreads();
  }
}

extern "C" void kernel_launch(void* const* d_in, const int* in_sizes, int n_in,
                              void* d_out, int out_size, void* d_ws, size_t ws_size,
                              hipStream_t stream) {
  (void)in_sizes; (void)n_in; (void)out_size; (void)ws_size;
  const float* imgE = (const float*)d_in[0];
  const float* txtE = (const float*)d_in[1];
  const void* xmask = d_in[2];
  const void* ymask = d_in[3];
  const float* W_img  = (const float*)d_in[4];
  const float* b_img  = (const float*)d_in[5];
  const float* W_txt  = (const float*)d_in[6];
  const float* b_txt  = (const float*)d_in[7];
  const float* W_img1 = (const float*)d_in[8];
  const float* b_img1 = (const float*)d_in[9];
  const float* W_txt1 = (const float*)d_in[10];
  const float* b_txt1 = (const float*)d_in[11];
  float* out_img = (float*)d_out;
  float* out_txt = out_img + (size_t)18874368;

  char* ws = (char*)d_ws;
  u16* Wt     = (u16*)(ws);                  // 4 x [1024][1024] bf16 (W^T)
  u16* imgA   = (u16*)(ws + 8388608);        // [18432][1024] bf16
  u16* txtA   = (u16*)(ws + 46137344);       // [25600][1024] bf16
  u16* Xb     = (u16*)(ws + 98566144);       // [18432][1024] bf16
  u16* Yb     = (u16*)(ws + 136314880);      // [25600][1024] bf16
  u16* gxw    = (u16*)(ws + 188743680);      // [18432][1024] bf16
  u16* gyw    = (u16*)(ws + 226492416);      // [25600][1024] bf16

  cast_k<<<2048, 256, 0, stream>>>((const float4*)imgE, imgA, 4718592);
  cast_k<<<2048, 256, 0, stream>>>((const float4*)txtE, txtA, 6553600);
  wtrans_k<<<dim3(32, 32, 4), 256, 0, stream>>>(W_img, W_txt, W_img1, W_txt1, Wt);
  gemm_k<0><<<dim3(8, 144), 256, 0, stream>>>(imgA, Wt,           b_img,  nullptr, Xb, nullptr, 18432);
  gemm_k<0><<<dim3(8, 200), 256, 0, stream>>>(txtA, Wt + 1048576, b_txt,  nullptr, Yb, nullptr, 25600);
  attn_k<<<512, 256, 0, stream>>>(Xb, Yb, imgA, txtA, xmask, ymask, gxw, gyw);
  gemm_k<1><<<dim3(8, 144), 256, 0, stream>>>(gxw, Wt + 2097152, b_img1, imgE, nullptr, out_img, 18432);
  gemm_k<1><<<dim3(8, 200), 256, 0, stream>>>(gyw, Wt + 3145728, b_txt1, txtE, nullptr, out_txt, 25600);
}

// Round 3
// 623.715 us; speedup vs baseline: 1.1594x; 1.1594x over previous
//
#include <hip/hip_runtime.h>

typedef unsigned short u16;
typedef unsigned int u32;
typedef __attribute__((ext_vector_type(8))) short sv8;   // 8 x bf16 (4 VGPR)
typedef __attribute__((ext_vector_type(4))) float fv4;   // MFMA accumulator

__device__ __forceinline__ u16 f2b(float f) {
  u32 u = __builtin_bit_cast(u32, f);
  u32 r = (u + 0x7fffu + ((u >> 16) & 1u)) >> 16;
  return (u16)r;
}
__device__ __forceinline__ float b2f(u16 h) {
  return __builtin_bit_cast(float, ((u32)h) << 16);
}
__device__ __forceinline__ void gld16(const void* g, void* l) {
  __builtin_amdgcn_global_load_lds(
      (const __attribute__((address_space(1))) u32*)g,
      (__attribute__((address_space(3))) u32*)l, 16, 0, 0);
}

// ---------------- cast f32 -> bf16 ----------------
__global__ __launch_bounds__(256) void cast_k(const float4* __restrict__ in,
                                              u16* __restrict__ out, int n4) {
  int i = blockIdx.x * 256 + threadIdx.x;
  const int stride = gridDim.x * 256;
  for (; i < n4; i += stride) {
    float4 v = in[i];
    u32 p0 = (u32)f2b(v.x) | ((u32)f2b(v.y) << 16);
    u32 p1 = (u32)f2b(v.z) | ((u32)f2b(v.w) << 16);
    uint2 o; o.x = p0; o.y = p1;
    ((uint2*)out)[i] = o;
  }
}

// ---------------- weight transpose + cast:  Wt[e][d] = W[d][e] ----------------
__global__ __launch_bounds__(256) void wtrans_k(const float* __restrict__ W0,
                                                const float* __restrict__ W1,
                                                const float* __restrict__ W2,
                                                const float* __restrict__ W3,
                                                u16* __restrict__ out) {
  const int z = blockIdx.z;
  const float* W = (z == 0) ? W0 : (z == 1) ? W1 : (z == 2) ? W2 : W3;
  u16* o = out + (size_t)z * 1048576;
  __shared__ float t[32][33];
  const int tid = threadIdx.x;
  const int r = tid >> 5, cc = tid & 31;
  const int d0 = blockIdx.x * 32, e0 = blockIdx.y * 32;
#pragma unroll
  for (int i = 0; i < 4; ++i)
    t[r + i * 8][cc] = W[(size_t)(d0 + r + i * 8) * 1024 + e0 + cc];
  __syncthreads();
#pragma unroll
  for (int i = 0; i < 4; ++i) {
    int row = r + i * 8;
    o[(size_t)(e0 + row) * 1024 + d0 + cc] = f2b(t[cc][row]);
  }
}

// ---------------- m97-style GEMM with XCD-bijective swizzle ----------------
// C[M,1024] = A[M,1024] * Bt[1024,1024]^T
// MODE 0: out = bf16(acc + bias)          -> outb
// MODE 1: out = acc + bias + resid (f32)  -> outf
// gridDim.x == 8, gridDim.y % 8 == 0. Swizzle: XCD k owns row-panels k mod 8,
// iterating all 8 col-tiles consecutively -> A-panel fetched by exactly 1 XCD.
template <int MODE>
__global__ __launch_bounds__(256) void gemm_k(const u16* __restrict__ A,
                                              const u16* __restrict__ Bt,
                                              const float* __restrict__ bias,
                                              const float* __restrict__ resid,
                                              u16* __restrict__ outb,
                                              float* __restrict__ outf, int M) {
  __shared__ u16 As[128 * 32];
  __shared__ u16 Bs[128 * 32];
  const int tid = threadIdx.x;
  const int lane = tid & 63;
  const int w = tid >> 6;
  const int l15 = lane & 15, l4 = lane >> 4;
  const int lin = blockIdx.y * 8 + blockIdx.x;
  const int xcd = lin & 7, slot = lin >> 3;
  const int bcol0 = (slot & 7) * 128;
  const int brow0 = (xcd + ((slot >> 3) << 3)) * 128;
  const int wr = (w >> 1) * 64;
  const int wc = (w & 1) * 64;
  fv4 acc[4][4] = {};

  const u32 off0 = (u32)tid * 16;
  const u32 off1 = off0 + 4096;
  const u32 r0 = off0 >> 6, c0b = off0 & 63;
  const u32 r1 = off1 >> 6, c1b = off1 & 63;
  const char* Ab = (const char*)A + (size_t)brow0 * 2048;
  const char* Bb = (const char*)Bt + (size_t)bcol0 * 2048;

  for (int k0 = 0; k0 < 1024; k0 += 32) {
    gld16(Ab + (size_t)r0 * 2048 + k0 * 2 + c0b, (char*)As + off0);
    gld16(Ab + (size_t)r1 * 2048 + k0 * 2 + c1b, (char*)As + off1);
    gld16(Bb + (size_t)r0 * 2048 + k0 * 2 + c0b, (char*)Bs + off0);
    gld16(Bb + (size_t)r1 * 2048 + k0 * 2 + c1b, (char*)Bs + off1);
    __syncthreads();
    sv8 a[4], bb[4];
#pragma unroll
    for (int m = 0; m < 4; ++m)
      a[m] = *(const sv8*)&As[(wr + m * 16 + l15) * 32 + l4 * 8];
#pragma unroll
    for (int n = 0; n < 4; ++n)
      bb[n] = *(const sv8*)&Bs[(wc + n * 16 + l15) * 32 + l4 * 8];
#pragma unroll
    for (int m = 0; m < 4; ++m)
#pragma unroll
      for (int n = 0; n < 4; ++n)
        acc[m][n] = __builtin_amdgcn_mfma_f32_16x16x32_bf16(a[m], bb[n], acc[m][n], 0, 0, 0);
    __syncthreads();
  }
#pragma unroll
  for (int n = 0; n < 4; ++n) {
    const int col = bcol0 + wc + n * 16 + l15;
    const float bv = bias[col];
#pragma unroll
    for (int m = 0; m < 4; ++m) {
      fv4 v = acc[m][n];
#pragma unroll
      for (int j = 0; j < 4; ++j) {
        const int row = brow0 + wr + m * 16 + l4 * 4 + j;
        const size_t idx = (size_t)row * 1024 + col;
        float r = v[j] + bv;
        if (MODE == 0) outb[idx] = f2b(r);
        else           outf[idx] = r + resid[idx];
      }
    }
  }
}

// ---------------- scores + masked softmax (one block per b) ----------------
// 512 threads: waves 4-7 compute the 48x64 score tile via global-fragment MFMA
// (wave w-4 owns col-tile tn, 3 row-tiles, K=1024: 4 loads + 3 MFMA per k-step,
// no LDS staging, no barriers in K-loop); waves 0-3 compute row norms.
// One barrier, then 8-lane-per-row parallel masked softmax; writes normalized
// P1 [36][64]f32 / P2 [50][64]f32 per b (only first 50/36 cols written/used).
__global__ __launch_bounds__(512) void score_k(const u16* __restrict__ Xb,
                                               const u16* __restrict__ Yb,
                                               const void* __restrict__ xmask,
                                               const void* __restrict__ ymask,
                                               float* __restrict__ P1g,
                                               float* __restrict__ P2g) {
  __shared__ float attL[48 * 65];        // stride 65 -> conflict-free col reads
  __shared__ float wxL[88];              // [0..35]=||x||, [36..85]=||y||
  __shared__ unsigned char msk[88];      // [0..35]=xm, [36..85]=ym
  const int b = blockIdx.x;
  const int tid = threadIdx.x;
  const int w = tid >> 6, lane = tid & 63;
  const int l15 = lane & 15, l4 = lane >> 4;

  // mask dtype auto-detect (int32 0/1 ORs to <=1; bytes OR to ~0x01010101)
  u32 det = 0;
  {
    const u32* mm = (const u32*)xmask;
#pragma unroll
    for (int i = 0; i < 16; ++i) det |= mm[i * 4];
    det |= mm[1] | mm[2] | mm[3];
  }
  const bool m_i32 = (det <= 1u);
  if (tid < 36)
    msk[tid] = (unsigned char)(m_i32 ? (((const int*)xmask)[b * 36 + tid] != 0)
                                     : (((const unsigned char*)xmask)[b * 36 + tid] != 0));
  if (tid >= 64 && tid < 114) {
    int m = tid - 64;
    msk[36 + m] = (unsigned char)(m_i32 ? (((const int*)ymask)[b * 50 + m] != 0)
                                        : (((const unsigned char*)ymask)[b * 50 + m] != 0));
  }

  const u16* Xr = Xb + (size_t)b * 36864;   // 36*1024
  const u16* Yr = Yb + (size_t)b * 51200;   // 50*1024

  if (w < 4) {
    // ---- row norms: 3 sweeps x (row = sweep*32 + tid>>3, part j = tid&7) ----
#pragma unroll
    for (int sweep = 0; sweep < 3; ++sweep) {
      int r = sweep * 32 + (tid >> 3);
      int j = tid & 7;
      if (r < 86) {
        const u32* p = (const u32*)((r < 36) ? (Xr + r * 1024)
                                             : (Yr + (size_t)(r - 36) * 1024)) + j * 64;
        float s = 0.f;
#pragma unroll
        for (int i = 0; i < 16; ++i) {
          uint4 q = ((const uint4*)p)[i];
          u32 qq[4] = {q.x, q.y, q.z, q.w};
#pragma unroll
          for (int k2 = 0; k2 < 4; ++k2) {
            float lo = __builtin_bit_cast(float, qq[k2] << 16);
            float hi = __builtin_bit_cast(float, qq[k2] & 0xffff0000u);
            s = fmaf(lo, lo, fmaf(hi, hi, s));
          }
        }
        s += __shfl_xor(s, 1); s += __shfl_xor(s, 2); s += __shfl_xor(s, 4);
        if (j == 0) wxL[r] = sqrtf(s);
      }
    }
  } else {
    // ---- scores: wave (w-4) owns col-tile tn; row-tiles tm=0..2 ----
    const int tn = w - 4;
    fv4 ac0 = {}, ac1 = {}, ac2 = {};
    const u16* Yp = Yr + (size_t)(tn * 16 + l15) * 1024 + l4 * 8;
    const u16* Xp = Xr + (size_t)l15 * 1024 + l4 * 8;
#pragma unroll 2
    for (int ks = 0; ks < 32; ++ks) {
      sv8 bf = *(const sv8*)(Yp + ks * 32);
      sv8 a0 = *(const sv8*)(Xp + ks * 32);
      sv8 a1 = *(const sv8*)(Xp + 16 * 1024 + ks * 32);
      sv8 a2 = *(const sv8*)(Xp + 32 * 1024 + ks * 32);
      ac0 = __builtin_amdgcn_mfma_f32_16x16x32_bf16(a0, bf, ac0, 0, 0, 0);
      ac1 = __builtin_amdgcn_mfma_f32_16x16x32_bf16(a1, bf, ac1, 0, 0, 0);
      ac2 = __builtin_amdgcn_mfma_f32_16x16x32_bf16(a2, bf, ac2, 0, 0, 0);
    }
    const int col = tn * 16 + l15;
#pragma unroll
    for (int j = 0; j < 4; ++j) {
      attL[(l4 * 4 + j) * 65 + col] = ac0[j];
      attL[(16 + l4 * 4 + j) * 65 + col] = ac1[j];
      attL[(32 + l4 * 4 + j) * 65 + col] = ac2[j];
    }
  }
  __syncthreads();

  // ---- parallel masked softmax: 2 sweeps of 64 rows, 8 lanes per row ----
#pragma unroll
  for (int sweep = 0; sweep < 2; ++sweep) {
    int R = sweep * 64 + (tid >> 3);
    int j = tid & 7;
    if (R < 36) {
      // img<-txt row n=R over m (masked by ym)
      float wxn = wxL[R];
      float sv[7];
#pragma unroll
      for (int i = 0; i < 7; ++i) {
        int m = j + i * 8;
        if (m < 50) {
          float den = fmaxf(wxn * wxL[36 + m], 1e-8f);
          float v = attL[R * 65 + m] / den;
          sv[i] = msk[36 + m] ? -1e9f : v;
        } else sv[i] = -3.4e38f;
      }
      float mx = sv[0];
#pragma unroll
      for (int i = 1; i < 7; ++i) mx = fmaxf(mx, sv[i]);
      mx = fmaxf(mx, __shfl_xor(mx, 1));
      mx = fmaxf(mx, __shfl_xor(mx, 2));
      mx = fmaxf(mx, __shfl_xor(mx, 4));
      float e[7], sum = 0.f;
#pragma unroll
      for (int i = 0; i < 7; ++i) {
        e[i] = (j + i * 8 < 50) ? __expf(sv[i] - mx) : 0.f;
        sum += e[i];
      }
      sum += __shfl_xor(sum, 1); sum += __shfl_xor(sum, 2); sum += __shfl_xor(sum, 4);
      float rs = 1.f / sum;
      float* dst = P1g + ((size_t)b * 36 + R) * 64;
#pragma unroll
      for (int i = 0; i < 7; ++i) {
        int m = j + i * 8;
        if (m < 50) dst[m] = e[i] * rs;
      }
    } else if (R < 86) {
      // txt<-img row m=R-36 over n (masked by xm)
      int m = R - 36;
      float wym = wxL[R];
      float sv[5];
#pragma unroll
      for (int i = 0; i < 5; ++i) {
        int n = j + i * 8;
        if (n < 36) {
          float den = fmaxf(wxL[n] * wym, 1e-8f);
          float v = attL[n * 65 + m] / den;
          sv[i] = msk[n] ? -1e9f : v;
        } else sv[i] = -3.4e38f;
      }
      float mx = sv[0];
#pragma unroll
      for (int i = 1; i < 5; ++i) mx = fmaxf(mx, sv[i]);
      mx = fmaxf(mx, __shfl_xor(mx, 1));
      mx = fmaxf(mx, __shfl_xor(mx, 2));
      mx = fmaxf(mx, __shfl_xor(mx, 4));
      float e[5], sum = 0.f;
#pragma unroll
      for (int i = 0; i < 5; ++i) {
        e[i] = (j + i * 8 < 36) ? __expf(sv[i] - mx) : 0.f;
        sum += e[i];
      }
      sum += __shfl_xor(sum, 1); sum += __shfl_xor(sum, 2); sum += __shfl_xor(sum, 4);
      float rs = 1.f / sum;
      float* dst = P2g + ((size_t)b * 50 + m) * 64;
#pragma unroll
      for (int i = 0; i < 5; ++i) {
        int n = j + i * 8;
        if (n < 36) dst[n] = e[i] * rs;
      }
    }
  }
}

// ---------------- P @ E + gate (thread = one d-column of one b) ----------------
// grid 2048 = 512 b x 4 d-chunks; E values live in VGPRs (tv[50], iv[36]);
// P rows read at wave-uniform addresses (-> scalar loads); no LDS.
__global__ __launch_bounds__(256) void pv_k(const float* __restrict__ P1g,
                                            const float* __restrict__ P2g,
                                            const u16* __restrict__ imgA,
                                            const u16* __restrict__ txtA,
                                            u16* __restrict__ gxw,
                                            u16* __restrict__ gyw) {
  const int b = blockIdx.x >> 2;
  const int d = ((blockIdx.x & 3) << 8) + threadIdx.x;
  const u16* tp = txtA + (size_t)b * 51200 + d;
  const u16* ip = imgA + (size_t)b * 36864 + d;
  float tv[50], iv[36];
#pragma unroll
  for (int m = 0; m < 50; ++m) tv[m] = b2f(tp[(size_t)m * 1024]);
#pragma unroll
  for (int n = 0; n < 36; ++n) iv[n] = b2f(ip[(size_t)n * 1024]);

  const float* __restrict__ P1 = P1g + (size_t)b * 2304;   // 36*64
  u16* gx = gxw + (size_t)b * 36864 + d;
  for (int n = 0; n < 36; ++n) {
    const float* __restrict__ pr = P1 + n * 64;
    float acc = 0.f;
#pragma unroll
    for (int m = 0; m < 50; ++m) acc = fmaf(pr[m], tv[m], acc);
    float t = acc * iv[n];
    float g = acc / (1.f + __expf(-t));
    gx[(size_t)n * 1024] = f2b(g);
  }
  const float* __restrict__ P2 = P2g + (size_t)b * 3200;   // 50*64
  u16* gy = gyw + (size_t)b * 51200 + d;
  for (int m = 0; m < 50; ++m) {
    const float* __restrict__ pr = P2 + m * 64;
    float acc = 0.f;
#pragma unroll
    for (int n = 0; n < 36; ++n) acc = fmaf(pr[n], iv[n], acc);
    float t = acc * tv[m];
    float g = acc / (1.f + __expf(-t));
    gy[(size_t)m * 1024] = f2b(g);
  }
}

extern "C" void kernel_launch(void* const* d_in, const int* in_sizes, int n_in,
                              void* d_out, int out_size, void* d_ws, size_t ws_size,
                              hipStream_t stream) {
  (void)in_sizes; (void)n_in; (void)out_size; (void)ws_size;
  const float* imgE = (const float*)d_in[0];
  const float* txtE = (const float*)d_in[1];
  const void* xmask = d_in[2];
  const void* ymask = d_in[3];
  const float* W_img  = (const float*)d_in[4];
  const float* b_img  = (const float*)d_in[5];
  const float* W_txt  = (const float*)d_in[6];
  const float* b_txt  = (const float*)d_in[7];
  const float* W_img1 = (const float*)d_in[8];
  const float* b_img1 = (const float*)d_in[9];
  const float* W_txt1 = (const float*)d_in[10];
  const float* b_txt1 = (const float*)d_in[11];
  float* out_img = (float*)d_out;
  float* out_txt = out_img + (size_t)18874368;

  char* ws = (char*)d_ws;
  u16* Wt   = (u16*)(ws);                    // 4 x [1024][1024] bf16 (W^T)
  u16* imgA = (u16*)(ws + 8388608);          // [18432][1024] bf16
  u16* txtA = (u16*)(ws + 46137344);         // [25600][1024] bf16
  u16* Xb   = (u16*)(ws + 98566144);         // [18432][1024] bf16 (dies after score_k)
  u16* Yb   = (u16*)(ws + 136314880);        // [25600][1024] bf16 (dies after score_k)
  float* P1g = (float*)(ws + 188743680);     // [512][36][64] f32
  float* P2g = (float*)(ws + 193462272);     // [512][50][64] f32
  u16* gxw  = (u16*)(ws + 98566144);         // reuses Xb slot
  u16* gyw  = (u16*)(ws + 136314880);        // reuses Yb slot

  cast_k<<<2048, 256, 0, stream>>>((const float4*)imgE, imgA, 4718592);
  cast_k<<<2048, 256, 0, stream>>>((const float4*)txtE, txtA, 6553600);
  wtrans_k<<<dim3(32, 32, 4), 256, 0, stream>>>(W_img, W_txt, W_img1, W_txt1, Wt);
  gemm_k<0><<<dim3(8, 144), 256, 0, stream>>>(imgA, Wt,           b_img, nullptr, Xb, nullptr, 18432);
  gemm_k<0><<<dim3(8, 200), 256, 0, stream>>>(txtA, Wt + 1048576, b_txt, nullptr, Yb, nullptr, 25600);
  score_k<<<512, 512, 0, stream>>>(Xb, Yb, xmask, ymask, P1g, P2g);
  pv_k<<<2048, 256, 0, stream>>>(P1g, P2g, imgA, txtA, gxw, gyw);
  gemm_k<1><<<dim3(8, 144), 256, 0, stream>>>(gxw, Wt + 2097152, b_img1, imgE, nullptr, out_img, 18432);
  gemm_k<1><<<dim3(8, 200), 256, 0, stream>>>(gyw, Wt + 3145728, b_txt1, txtE, nullptr, out_txt, 25600);
}

// Round 4
// 609.288 us; speedup vs baseline: 1.1868x; 1.0237x over previous
//
#include <hip/hip_runtime.h>

typedef unsigned short u16;
typedef unsigned int u32;
typedef __attribute__((ext_vector_type(8))) short sv8;   // 8 x bf16 (4 VGPR)
typedef __attribute__((ext_vector_type(4))) float fv4;   // MFMA accumulator

__device__ __forceinline__ u16 f2b(float f) {
  u32 u = __builtin_bit_cast(u32, f);
  u32 r = (u + 0x7fffu + ((u >> 16) & 1u)) >> 16;
  return (u16)r;
}
__device__ __forceinline__ float b2f(u16 h) {
  return __builtin_bit_cast(float, ((u32)h) << 16);
}
__device__ __forceinline__ void gld16(const void* g, void* l) {
  __builtin_amdgcn_global_load_lds(
      (const __attribute__((address_space(1))) u32*)g,
      (__attribute__((address_space(3))) u32*)l, 16, 0, 0);
}

// ---------------- cast f32 -> bf16 ----------------
__global__ __launch_bounds__(256) void cast_k(const float4* __restrict__ in,
                                              u16* __restrict__ out, int n4) {
  int i = blockIdx.x * 256 + threadIdx.x;
  const int stride = gridDim.x * 256;
  for (; i < n4; i += stride) {
    float4 v = in[i];
    u32 p0 = (u32)f2b(v.x) | ((u32)f2b(v.y) << 16);
    u32 p1 = (u32)f2b(v.z) | ((u32)f2b(v.w) << 16);
    uint2 o; o.x = p0; o.y = p1;
    ((uint2*)out)[i] = o;
  }
}

// ---------------- weight transpose + cast:  Wt[e][d] = W[d][e] ----------------
__global__ __launch_bounds__(256) void wtrans_k(const float* __restrict__ W0,
                                                const float* __restrict__ W1,
                                                const float* __restrict__ W2,
                                                const float* __restrict__ W3,
                                                u16* __restrict__ out) {
  const int z = blockIdx.z;
  const float* W = (z == 0) ? W0 : (z == 1) ? W1 : (z == 2) ? W2 : W3;
  u16* o = out + (size_t)z * 1048576;
  __shared__ float t[32][33];
  const int tid = threadIdx.x;
  const int r = tid >> 5, cc = tid & 31;
  const int d0 = blockIdx.x * 32, e0 = blockIdx.y * 32;
#pragma unroll
  for (int i = 0; i < 4; ++i)
    t[r + i * 8][cc] = W[(size_t)(d0 + r + i * 8) * 1024 + e0 + cc];
  __syncthreads();
#pragma unroll
  for (int i = 0; i < 4; ++i) {
    int row = r + i * 8;
    o[(size_t)(e0 + row) * 1024 + d0 + cc] = f2b(t[cc][row]);
  }
}

// ---------------- m97-style GEMM with XCD-bijective swizzle ----------------
// C[M,1024] = A[M,1024] * Bt[1024,1024]^T
// MODE 0: out = bf16(acc + bias)          -> outb
// MODE 1: out = acc + bias + resid (f32)  -> outf
// gridDim.x == 8, gridDim.y % 8 == 0. Swizzle: XCD k owns row-panels k mod 8,
// iterating all 8 col-tiles consecutively -> A-panel fetched by exactly 1 XCD.
template <int MODE>
__global__ __launch_bounds__(256) void gemm_k(const u16* __restrict__ A,
                                              const u16* __restrict__ Bt,
                                              const float* __restrict__ bias,
                                              const float* __restrict__ resid,
                                              u16* __restrict__ outb,
                                              float* __restrict__ outf, int M) {
  __shared__ u16 As[128 * 32];
  __shared__ u16 Bs[128 * 32];
  const int tid = threadIdx.x;
  const int lane = tid & 63;
  const int w = tid >> 6;
  const int l15 = lane & 15, l4 = lane >> 4;
  const int lin = blockIdx.y * 8 + blockIdx.x;
  const int xcd = lin & 7, slot = lin >> 3;
  const int bcol0 = (slot & 7) * 128;
  const int brow0 = (xcd + ((slot >> 3) << 3)) * 128;
  const int wr = (w >> 1) * 64;
  const int wc = (w & 1) * 64;
  fv4 acc[4][4] = {};

  const u32 off0 = (u32)tid * 16;
  const u32 off1 = off0 + 4096;
  const u32 r0 = off0 >> 6, c0b = off0 & 63;
  const u32 r1 = off1 >> 6, c1b = off1 & 63;
  const char* Ab = (const char*)A + (size_t)brow0 * 2048;
  const char* Bb = (const char*)Bt + (size_t)bcol0 * 2048;

  for (int k0 = 0; k0 < 1024; k0 += 32) {
    gld16(Ab + (size_t)r0 * 2048 + k0 * 2 + c0b, (char*)As + off0);
    gld16(Ab + (size_t)r1 * 2048 + k0 * 2 + c1b, (char*)As + off1);
    gld16(Bb + (size_t)r0 * 2048 + k0 * 2 + c0b, (char*)Bs + off0);
    gld16(Bb + (size_t)r1 * 2048 + k0 * 2 + c1b, (char*)Bs + off1);
    __syncthreads();
    sv8 a[4], bb[4];
#pragma unroll
    for (int m = 0; m < 4; ++m)
      a[m] = *(const sv8*)&As[(wr + m * 16 + l15) * 32 + l4 * 8];
#pragma unroll
    for (int n = 0; n < 4; ++n)
      bb[n] = *(const sv8*)&Bs[(wc + n * 16 + l15) * 32 + l4 * 8];
#pragma unroll
    for (int m = 0; m < 4; ++m)
#pragma unroll
      for (int n = 0; n < 4; ++n)
        acc[m][n] = __builtin_amdgcn_mfma_f32_16x16x32_bf16(a[m], bb[n], acc[m][n], 0, 0, 0);
    __syncthreads();
  }
#pragma unroll
  for (int n = 0; n < 4; ++n) {
    const int col = bcol0 + wc + n * 16 + l15;
    const float bv = bias[col];
#pragma unroll
    for (int m = 0; m < 4; ++m) {
      fv4 v = acc[m][n];
#pragma unroll
      for (int j = 0; j < 4; ++j) {
        const int row = brow0 + wr + m * 16 + l4 * 4 + j;
        const size_t idx = (size_t)row * 1024 + col;
        float r = v[j] + bv;
        if (MODE == 0) outb[idx] = f2b(r);
        else           outf[idx] = r + resid[idx];
      }
    }
  }
}

// ---------------- scores + masked softmax (one block per b) ----------------
__global__ __launch_bounds__(512) void score_k(const u16* __restrict__ Xb,
                                               const u16* __restrict__ Yb,
                                               const void* __restrict__ xmask,
                                               const void* __restrict__ ymask,
                                               float* __restrict__ P1g,
                                               float* __restrict__ P2g) {
  __shared__ float attL[48 * 65];        // stride 65 -> conflict-free col reads
  __shared__ float wxL[88];              // [0..35]=||x||, [36..85]=||y||
  __shared__ unsigned char msk[88];      // [0..35]=xm, [36..85]=ym
  const int b = blockIdx.x;
  const int tid = threadIdx.x;
  const int w = tid >> 6, lane = tid & 63;
  const int l15 = lane & 15, l4 = lane >> 4;

  // mask dtype auto-detect (int32 0/1 ORs to <=1; bytes OR to ~0x01010101)
  u32 det = 0;
  {
    const u32* mm = (const u32*)xmask;
#pragma unroll
    for (int i = 0; i < 16; ++i) det |= mm[i * 4];
    det |= mm[1] | mm[2] | mm[3];
  }
  const bool m_i32 = (det <= 1u);
  if (tid < 36)
    msk[tid] = (unsigned char)(m_i32 ? (((const int*)xmask)[b * 36 + tid] != 0)
                                     : (((const unsigned char*)xmask)[b * 36 + tid] != 0));
  if (tid >= 64 && tid < 114) {
    int m = tid - 64;
    msk[36 + m] = (unsigned char)(m_i32 ? (((const int*)ymask)[b * 50 + m] != 0)
                                        : (((const unsigned char*)ymask)[b * 50 + m] != 0));
  }

  const u16* Xr = Xb + (size_t)b * 36864;   // 36*1024
  const u16* Yr = Yb + (size_t)b * 51200;   // 50*1024

  if (w < 4) {
    // ---- row norms: 3 sweeps x (row = sweep*32 + tid>>3, part j = tid&7) ----
#pragma unroll
    for (int sweep = 0; sweep < 3; ++sweep) {
      int r = sweep * 32 + (tid >> 3);
      int j = tid & 7;
      if (r < 86) {
        const u32* p = (const u32*)((r < 36) ? (Xr + r * 1024)
                                             : (Yr + (size_t)(r - 36) * 1024)) + j * 64;
        float s = 0.f;
#pragma unroll
        for (int i = 0; i < 16; ++i) {
          uint4 q = ((const uint4*)p)[i];
          u32 qq[4] = {q.x, q.y, q.z, q.w};
#pragma unroll
          for (int k2 = 0; k2 < 4; ++k2) {
            float lo = __builtin_bit_cast(float, qq[k2] << 16);
            float hi = __builtin_bit_cast(float, qq[k2] & 0xffff0000u);
            s = fmaf(lo, lo, fmaf(hi, hi, s));
          }
        }
        s += __shfl_xor(s, 1); s += __shfl_xor(s, 2); s += __shfl_xor(s, 4);
        if (j == 0) wxL[r] = sqrtf(s);
      }
    }
  } else {
    // ---- scores: wave (w-4) owns col-tile tn; row-tiles tm=0..2 ----
    const int tn = w - 4;
    fv4 ac0 = {}, ac1 = {}, ac2 = {};
    const u16* Yp = Yr + (size_t)(tn * 16 + l15) * 1024 + l4 * 8;
    const u16* Xp = Xr + (size_t)l15 * 1024 + l4 * 8;
#pragma unroll 2
    for (int ks = 0; ks < 32; ++ks) {
      sv8 bf = *(const sv8*)(Yp + ks * 32);
      sv8 a0 = *(const sv8*)(Xp + ks * 32);
      sv8 a1 = *(const sv8*)(Xp + 16 * 1024 + ks * 32);
      sv8 a2 = *(const sv8*)(Xp + 32 * 1024 + ks * 32);
      ac0 = __builtin_amdgcn_mfma_f32_16x16x32_bf16(a0, bf, ac0, 0, 0, 0);
      ac1 = __builtin_amdgcn_mfma_f32_16x16x32_bf16(a1, bf, ac1, 0, 0, 0);
      ac2 = __builtin_amdgcn_mfma_f32_16x16x32_bf16(a2, bf, ac2, 0, 0, 0);
    }
    const int col = tn * 16 + l15;
#pragma unroll
    for (int j = 0; j < 4; ++j) {
      attL[(l4 * 4 + j) * 65 + col] = ac0[j];
      attL[(16 + l4 * 4 + j) * 65 + col] = ac1[j];
      attL[(32 + l4 * 4 + j) * 65 + col] = ac2[j];
    }
  }
  __syncthreads();

  // ---- parallel masked softmax: 2 sweeps of 64 rows, 8 lanes per row ----
#pragma unroll
  for (int sweep = 0; sweep < 2; ++sweep) {
    int R = sweep * 64 + (tid >> 3);
    int j = tid & 7;
    if (R < 36) {
      // img<-txt row n=R over m (masked by ym)
      float wxn = wxL[R];
      float sv[7];
#pragma unroll
      for (int i = 0; i < 7; ++i) {
        int m = j + i * 8;
        if (m < 50) {
          float den = fmaxf(wxn * wxL[36 + m], 1e-8f);
          float v = attL[R * 65 + m] / den;
          sv[i] = msk[36 + m] ? -1e9f : v;
        } else sv[i] = -3.4e38f;
      }
      float mx = sv[0];
#pragma unroll
      for (int i = 1; i < 7; ++i) mx = fmaxf(mx, sv[i]);
      mx = fmaxf(mx, __shfl_xor(mx, 1));
      mx = fmaxf(mx, __shfl_xor(mx, 2));
      mx = fmaxf(mx, __shfl_xor(mx, 4));
      float e[7], sum = 0.f;
#pragma unroll
      for (int i = 0; i < 7; ++i) {
        e[i] = (j + i * 8 < 50) ? __expf(sv[i] - mx) : 0.f;
        sum += e[i];
      }
      sum += __shfl_xor(sum, 1); sum += __shfl_xor(sum, 2); sum += __shfl_xor(sum, 4);
      float rs = 1.f / sum;
      float* dst = P1g + ((size_t)b * 36 + R) * 64;
#pragma unroll
      for (int i = 0; i < 7; ++i) {
        int m = j + i * 8;
        if (m < 50) dst[m] = e[i] * rs;
      }
    } else if (R < 86) {
      // txt<-img row m=R-36 over n (masked by xm)
      int m = R - 36;
      float wym = wxL[R];
      float sv[5];
#pragma unroll
      for (int i = 0; i < 5; ++i) {
        int n = j + i * 8;
        if (n < 36) {
          float den = fmaxf(wxL[n] * wym, 1e-8f);
          float v = attL[n * 65 + m] / den;
          sv[i] = msk[n] ? -1e9f : v;
        } else sv[i] = -3.4e38f;
      }
      float mx = sv[0];
#pragma unroll
      for (int i = 1; i < 5; ++i) mx = fmaxf(mx, sv[i]);
      mx = fmaxf(mx, __shfl_xor(mx, 1));
      mx = fmaxf(mx, __shfl_xor(mx, 2));
      mx = fmaxf(mx, __shfl_xor(mx, 4));
      float e[5], sum = 0.f;
#pragma unroll
      for (int i = 0; i < 5; ++i) {
        e[i] = (j + i * 8 < 36) ? __expf(sv[i] - mx) : 0.f;
        sum += e[i];
      }
      sum += __shfl_xor(sum, 1); sum += __shfl_xor(sum, 2); sum += __shfl_xor(sum, 4);
      float rs = 1.f / sum;
      float* dst = P2g + ((size_t)b * 50 + m) * 64;
#pragma unroll
      for (int i = 0; i < 5; ++i) {
        int n = j + i * 8;
        if (n < 36) dst[n] = e[i] * rs;
      }
    }
  }
}

// ---------------- P @ E + gate (thread = one d-column of one b) ----------------
// grid 2048, CHUNK-MAJOR: b = bid & 511, chunk = bid >> 9 -> the 4 blocks of a
// given b are 512 apart (512 % 8 == 0 -> same XCD) so P1[b]/P2[b] is fetched
// into one XCD's L2 once. Outer loops FULLY UNROLLED so tv[]/iv[] are
// static-indexed -> stay in VGPRs (R3: runtime index -> scratch, 3x WRITE).
// P-row reads are block-uniform -> scalar loads; v_fmac v,s,v (1 SGPR/op ok).
__global__ __launch_bounds__(256) void pv_k(const float* __restrict__ P1g,
                                            const float* __restrict__ P2g,
                                            const u16* __restrict__ imgA,
                                            const u16* __restrict__ txtA,
                                            u16* __restrict__ gxw,
                                            u16* __restrict__ gyw) {
  const int b = blockIdx.x & 511;
  const int d = ((blockIdx.x >> 9) << 8) + threadIdx.x;
  const u16* tp = txtA + (size_t)b * 51200 + d;
  const u16* ip = imgA + (size_t)b * 36864 + d;
  float tv[50], iv[36];
#pragma unroll
  for (int m = 0; m < 50; ++m) tv[m] = b2f(tp[(size_t)m * 1024]);
#pragma unroll
  for (int n = 0; n < 36; ++n) iv[n] = b2f(ip[(size_t)n * 1024]);

  const float* __restrict__ P1 = P1g + (size_t)b * 2304;   // 36*64
  u16* gx = gxw + (size_t)b * 36864 + d;
#pragma unroll
  for (int n = 0; n < 36; ++n) {
    const float* __restrict__ pr = P1 + n * 64;
    float acc = 0.f;
#pragma unroll
    for (int m = 0; m < 50; ++m) acc = fmaf(pr[m], tv[m], acc);
    float t = acc * iv[n];
    float g = acc / (1.f + __expf(-t));
    gx[(size_t)n * 1024] = f2b(g);
  }
  const float* __restrict__ P2 = P2g + (size_t)b * 3200;   // 50*64
  u16* gy = gyw + (size_t)b * 51200 + d;
#pragma unroll
  for (int m = 0; m < 50; ++m) {
    const float* __restrict__ pr = P2 + m * 64;
    float acc = 0.f;
#pragma unroll
    for (int n = 0; n < 36; ++n) acc = fmaf(pr[n], iv[n], acc);
    float t = acc * tv[m];
    float g = acc / (1.f + __expf(-t));
    gy[(size_t)m * 1024] = f2b(g);
  }
}

extern "C" void kernel_launch(void* const* d_in, const int* in_sizes, int n_in,
                              void* d_out, int out_size, void* d_ws, size_t ws_size,
                              hipStream_t stream) {
  (void)in_sizes; (void)n_in; (void)out_size; (void)ws_size;
  const float* imgE = (const float*)d_in[0];
  const float* txtE = (const float*)d_in[1];
  const void* xmask = d_in[2];
  const void* ymask = d_in[3];
  const float* W_img  = (const float*)d_in[4];
  const float* b_img  = (const float*)d_in[5];
  const float* W_txt  = (const float*)d_in[6];
  const float* b_txt  = (const float*)d_in[7];
  const float* W_img1 = (const float*)d_in[8];
  const float* b_img1 = (const float*)d_in[9];
  const float* W_txt1 = (const float*)d_in[10];
  const float* b_txt1 = (const float*)d_in[11];
  float* out_img = (float*)d_out;
  float* out_txt = out_img + (size_t)18874368;

  char* ws = (char*)d_ws;
  u16* Wt   = (u16*)(ws);                    // 4 x [1024][1024] bf16 (W^T)
  u16* imgA = (u16*)(ws + 8388608);          // [18432][1024] bf16
  u16* txtA = (u16*)(ws + 46137344);         // [25600][1024] bf16
  u16* Xb   = (u16*)(ws + 98566144);         // [18432][1024] bf16 (dies after score_k)
  u16* Yb   = (u16*)(ws + 136314880);        // [25600][1024] bf16 (dies after score_k)
  float* P1g = (float*)(ws + 188743680);     // [512][36][64] f32
  float* P2g = (float*)(ws + 193462272);     // [512][50][64] f32
  u16* gxw  = (u16*)(ws + 98566144);         // reuses Xb slot
  u16* gyw  = (u16*)(ws + 136314880);        // reuses Yb slot

  cast_k<<<2048, 256, 0, stream>>>((const float4*)imgE, imgA, 4718592);
  cast_k<<<2048, 256, 0, stream>>>((const float4*)txtE, txtA, 6553600);
  wtrans_k<<<dim3(32, 32, 4), 256, 0, stream>>>(W_img, W_txt, W_img1, W_txt1, Wt);
  gemm_k<0><<<dim3(8, 144), 256, 0, stream>>>(imgA, Wt,           b_img, nullptr, Xb, nullptr, 18432);
  gemm_k<0><<<dim3(8, 200), 256, 0, stream>>>(txtA, Wt + 1048576, b_txt, nullptr, Yb, nullptr, 25600);
  score_k<<<512, 512, 0, stream>>>(Xb, Yb, xmask, ymask, P1g, P2g);
  pv_k<<<2048, 256, 0, stream>>>(P1g, P2g, imgA, txtA, gxw, gyw);
  gemm_k<1><<<dim3(8, 144), 256, 0, stream>>>(gxw, Wt + 2097152, b_img1, imgE, nullptr, out_img, 18432);
  gemm_k<1><<<dim3(8, 200), 256, 0, stream>>>(gyw, Wt + 3145728, b_txt1, txtE, nullptr, out_txt, 25600);
}

// Round 5
// 533.867 us; speedup vs baseline: 1.3545x; 1.1413x over previous
//
#include <hip/hip_runtime.h>

typedef unsigned short u16;
typedef unsigned int u32;
typedef __attribute__((ext_vector_type(8))) short sv8;   // 8 x bf16 (4 VGPR)
typedef __attribute__((ext_vector_type(4))) float fv4;   // MFMA accumulator

__device__ __forceinline__ u16 f2b(float f) {
  u32 u = __builtin_bit_cast(u32, f);
  u32 r = (u + 0x7fffu + ((u >> 16) & 1u)) >> 16;
  return (u16)r;
}
__device__ __forceinline__ float b2f(u16 h) {
  return __builtin_bit_cast(float, ((u32)h) << 16);
}
__device__ __forceinline__ void gld16(const void* g, void* l) {
  __builtin_amdgcn_global_load_lds(
      (const __attribute__((address_space(1))) u32*)g,
      (__attribute__((address_space(3))) u32*)l, 16, 0, 0);
}

// ---------------- cast f32 -> bf16 ----------------
__global__ __launch_bounds__(256) void cast_k(const float4* __restrict__ in,
                                              u16* __restrict__ out, int n4) {
  int i = blockIdx.x * 256 + threadIdx.x;
  const int stride = gridDim.x * 256;
  for (; i < n4; i += stride) {
    float4 v = in[i];
    u32 p0 = (u32)f2b(v.x) | ((u32)f2b(v.y) << 16);
    u32 p1 = (u32)f2b(v.z) | ((u32)f2b(v.w) << 16);
    uint2 o; o.x = p0; o.y = p1;
    ((uint2*)out)[i] = o;
  }
}

// ---------------- weight transpose + cast:  Wt[e][d] = W[d][e] ----------------
__global__ __launch_bounds__(256) void wtrans_k(const float* __restrict__ W0,
                                                const float* __restrict__ W1,
                                                const float* __restrict__ W2,
                                                const float* __restrict__ W3,
                                                u16* __restrict__ out) {
  const int z = blockIdx.z;
  const float* W = (z == 0) ? W0 : (z == 1) ? W1 : (z == 2) ? W2 : W3;
  u16* o = out + (size_t)z * 1048576;
  __shared__ float t[32][33];
  const int tid = threadIdx.x;
  const int r = tid >> 5, cc = tid & 31;
  const int d0 = blockIdx.x * 32, e0 = blockIdx.y * 32;
#pragma unroll
  for (int i = 0; i < 4; ++i)
    t[r + i * 8][cc] = W[(size_t)(d0 + r + i * 8) * 1024 + e0 + cc];
  __syncthreads();
#pragma unroll
  for (int i = 0; i < 4; ++i) {
    int row = r + i * 8;
    o[(size_t)(e0 + row) * 1024 + d0 + cc] = f2b(t[cc][row]);
  }
}

// ---------------- m97-style GEMM with XCD-bijective swizzle ----------------
// C[M,1024] = A[M,1024] * Bt[1024,1024]^T
// MODE 0: out = bf16(acc + bias)          -> outb
// MODE 1: out = acc + bias + resid (f32)  -> outf
template <int MODE>
__global__ __launch_bounds__(256) void gemm_k(const u16* __restrict__ A,
                                              const u16* __restrict__ Bt,
                                              const float* __restrict__ bias,
                                              const float* __restrict__ resid,
                                              u16* __restrict__ outb,
                                              float* __restrict__ outf, int M) {
  __shared__ u16 As[128 * 32];
  __shared__ u16 Bs[128 * 32];
  const int tid = threadIdx.x;
  const int lane = tid & 63;
  const int w = tid >> 6;
  const int l15 = lane & 15, l4 = lane >> 4;
  const int lin = blockIdx.y * 8 + blockIdx.x;
  const int xcd = lin & 7, slot = lin >> 3;
  const int bcol0 = (slot & 7) * 128;
  const int brow0 = (xcd + ((slot >> 3) << 3)) * 128;
  const int wr = (w >> 1) * 64;
  const int wc = (w & 1) * 64;
  fv4 acc[4][4] = {};

  const u32 off0 = (u32)tid * 16;
  const u32 off1 = off0 + 4096;
  const u32 r0 = off0 >> 6, c0b = off0 & 63;
  const u32 r1 = off1 >> 6, c1b = off1 & 63;
  const char* Ab = (const char*)A + (size_t)brow0 * 2048;
  const char* Bb = (const char*)Bt + (size_t)bcol0 * 2048;

  for (int k0 = 0; k0 < 1024; k0 += 32) {
    gld16(Ab + (size_t)r0 * 2048 + k0 * 2 + c0b, (char*)As + off0);
    gld16(Ab + (size_t)r1 * 2048 + k0 * 2 + c1b, (char*)As + off1);
    gld16(Bb + (size_t)r0 * 2048 + k0 * 2 + c0b, (char*)Bs + off0);
    gld16(Bb + (size_t)r1 * 2048 + k0 * 2 + c1b, (char*)Bs + off1);
    __syncthreads();
    sv8 a[4], bb[4];
#pragma unroll
    for (int m = 0; m < 4; ++m)
      a[m] = *(const sv8*)&As[(wr + m * 16 + l15) * 32 + l4 * 8];
#pragma unroll
    for (int n = 0; n < 4; ++n)
      bb[n] = *(const sv8*)&Bs[(wc + n * 16 + l15) * 32 + l4 * 8];
#pragma unroll
    for (int m = 0; m < 4; ++m)
#pragma unroll
      for (int n = 0; n < 4; ++n)
        acc[m][n] = __builtin_amdgcn_mfma_f32_16x16x32_bf16(a[m], bb[n], acc[m][n], 0, 0, 0);
    __syncthreads();
  }
#pragma unroll
  for (int n = 0; n < 4; ++n) {
    const int col = bcol0 + wc + n * 16 + l15;
    const float bv = bias[col];
#pragma unroll
    for (int m = 0; m < 4; ++m) {
      fv4 v = acc[m][n];
#pragma unroll
      for (int j = 0; j < 4; ++j) {
        const int row = brow0 + wr + m * 16 + l4 * 4 + j;
        const size_t idx = (size_t)row * 1024 + col;
        float r = v[j] + bv;
        if (MODE == 0) outb[idx] = f2b(r);
        else           outf[idx] = r + resid[idx];
      }
    }
  }
}

// ---------------- scores + masked softmax (one block per b) ----------------
__global__ __launch_bounds__(512) void score_k(const u16* __restrict__ Xb,
                                               const u16* __restrict__ Yb,
                                               const void* __restrict__ xmask,
                                               const void* __restrict__ ymask,
                                               float* __restrict__ P1g,
                                               float* __restrict__ P2g) {
  __shared__ float attL[48 * 65];        // stride 65 -> conflict-free col reads
  __shared__ float wxL[88];              // [0..35]=||x||, [36..85]=||y||
  __shared__ unsigned char msk[88];      // [0..35]=xm, [36..85]=ym
  const int b = blockIdx.x;
  const int tid = threadIdx.x;
  const int w = tid >> 6, lane = tid & 63;
  const int l15 = lane & 15, l4 = lane >> 4;

  // mask dtype auto-detect (int32 0/1 ORs to <=1; bytes OR to ~0x01010101)
  u32 det = 0;
  {
    const u32* mm = (const u32*)xmask;
#pragma unroll
    for (int i = 0; i < 16; ++i) det |= mm[i * 4];
    det |= mm[1] | mm[2] | mm[3];
  }
  const bool m_i32 = (det <= 1u);
  if (tid < 36)
    msk[tid] = (unsigned char)(m_i32 ? (((const int*)xmask)[b * 36 + tid] != 0)
                                     : (((const unsigned char*)xmask)[b * 36 + tid] != 0));
  if (tid >= 64 && tid < 114) {
    int m = tid - 64;
    msk[36 + m] = (unsigned char)(m_i32 ? (((const int*)ymask)[b * 50 + m] != 0)
                                        : (((const unsigned char*)ymask)[b * 50 + m] != 0));
  }

  const u16* Xr = Xb + (size_t)b * 36864;   // 36*1024
  const u16* Yr = Yb + (size_t)b * 51200;   // 50*1024

  if (w < 4) {
    // ---- row norms: 3 sweeps x (row = sweep*32 + tid>>3, part j = tid&7) ----
#pragma unroll
    for (int sweep = 0; sweep < 3; ++sweep) {
      int r = sweep * 32 + (tid >> 3);
      int j = tid & 7;
      if (r < 86) {
        const u32* p = (const u32*)((r < 36) ? (Xr + r * 1024)
                                             : (Yr + (size_t)(r - 36) * 1024)) + j * 64;
        float s = 0.f;
#pragma unroll
        for (int i = 0; i < 16; ++i) {
          uint4 q = ((const uint4*)p)[i];
          u32 qq[4] = {q.x, q.y, q.z, q.w};
#pragma unroll
          for (int k2 = 0; k2 < 4; ++k2) {
            float lo = __builtin_bit_cast(float, qq[k2] << 16);
            float hi = __builtin_bit_cast(float, qq[k2] & 0xffff0000u);
            s = fmaf(lo, lo, fmaf(hi, hi, s));
          }
        }
        s += __shfl_xor(s, 1); s += __shfl_xor(s, 2); s += __shfl_xor(s, 4);
        if (j == 0) wxL[r] = sqrtf(s);
      }
    }
  } else {
    // ---- scores: wave (w-4) owns col-tile tn; row-tiles tm=0..2 ----
    const int tn = w - 4;
    fv4 ac0 = {}, ac1 = {}, ac2 = {};
    const u16* Yp = Yr + (size_t)(tn * 16 + l15) * 1024 + l4 * 8;
    const u16* Xp = Xr + (size_t)l15 * 1024 + l4 * 8;
#pragma unroll 2
    for (int ks = 0; ks < 32; ++ks) {
      sv8 bf = *(const sv8*)(Yp + ks * 32);
      sv8 a0 = *(const sv8*)(Xp + ks * 32);
      sv8 a1 = *(const sv8*)(Xp + 16 * 1024 + ks * 32);
      sv8 a2 = *(const sv8*)(Xp + 32 * 1024 + ks * 32);
      ac0 = __builtin_amdgcn_mfma_f32_16x16x32_bf16(a0, bf, ac0, 0, 0, 0);
      ac1 = __builtin_amdgcn_mfma_f32_16x16x32_bf16(a1, bf, ac1, 0, 0, 0);
      ac2 = __builtin_amdgcn_mfma_f32_16x16x32_bf16(a2, bf, ac2, 0, 0, 0);
    }
    const int col = tn * 16 + l15;
#pragma unroll
    for (int j = 0; j < 4; ++j) {
      attL[(l4 * 4 + j) * 65 + col] = ac0[j];
      attL[(16 + l4 * 4 + j) * 65 + col] = ac1[j];
      attL[(32 + l4 * 4 + j) * 65 + col] = ac2[j];
    }
  }
  __syncthreads();

  // ---- parallel masked softmax: 2 sweeps of 64 rows, 8 lanes per row ----
#pragma unroll
  for (int sweep = 0; sweep < 2; ++sweep) {
    int R = sweep * 64 + (tid >> 3);
    int j = tid & 7;
    if (R < 36) {
      // img<-txt row n=R over m (masked by ym)
      float wxn = wxL[R];
      float sv[7];
#pragma unroll
      for (int i = 0; i < 7; ++i) {
        int m = j + i * 8;
        if (m < 50) {
          float den = fmaxf(wxn * wxL[36 + m], 1e-8f);
          float v = attL[R * 65 + m] / den;
          sv[i] = msk[36 + m] ? -1e9f : v;
        } else sv[i] = -3.4e38f;
      }
      float mx = sv[0];
#pragma unroll
      for (int i = 1; i < 7; ++i) mx = fmaxf(mx, sv[i]);
      mx = fmaxf(mx, __shfl_xor(mx, 1));
      mx = fmaxf(mx, __shfl_xor(mx, 2));
      mx = fmaxf(mx, __shfl_xor(mx, 4));
      float e[7], sum = 0.f;
#pragma unroll
      for (int i = 0; i < 7; ++i) {
        e[i] = (j + i * 8 < 50) ? __expf(sv[i] - mx) : 0.f;
        sum += e[i];
      }
      sum += __shfl_xor(sum, 1); sum += __shfl_xor(sum, 2); sum += __shfl_xor(sum, 4);
      float rs = 1.f / sum;
      float* dst = P1g + ((size_t)b * 36 + R) * 64;
#pragma unroll
      for (int i = 0; i < 7; ++i) {
        int m = j + i * 8;
        if (m < 50) dst[m] = e[i] * rs;
      }
    } else if (R < 86) {
      // txt<-img row m=R-36 over n (masked by xm)
      int m = R - 36;
      float wym = wxL[R];
      float sv[5];
#pragma unroll
      for (int i = 0; i < 5; ++i) {
        int n = j + i * 8;
        if (n < 36) {
          float den = fmaxf(wxL[n] * wym, 1e-8f);
          float v = attL[n * 65 + m] / den;
          sv[i] = msk[n] ? -1e9f : v;
        } else sv[i] = -3.4e38f;
      }
      float mx = sv[0];
#pragma unroll
      for (int i = 1; i < 5; ++i) mx = fmaxf(mx, sv[i]);
      mx = fmaxf(mx, __shfl_xor(mx, 1));
      mx = fmaxf(mx, __shfl_xor(mx, 2));
      mx = fmaxf(mx, __shfl_xor(mx, 4));
      float e[5], sum = 0.f;
#pragma unroll
      for (int i = 0; i < 5; ++i) {
        e[i] = (j + i * 8 < 36) ? __expf(sv[i] - mx) : 0.f;
        sum += e[i];
      }
      sum += __shfl_xor(sum, 1); sum += __shfl_xor(sum, 2); sum += __shfl_xor(sum, 4);
      float rs = 1.f / sum;
      float* dst = P2g + ((size_t)b * 50 + m) * 64;
#pragma unroll
      for (int i = 0; i < 5; ++i) {
        int n = j + i * 8;
        if (n < 36) dst[n] = e[i] * rs;
      }
    }
  }
}

// ---------------- P @ E + gate (thread = one d-column of one b) ----------------
// R4 lesson: per-lane broadcast global loads of P rows = 3600 VMEM instrs/thread
// -> VMEM-issue-bound (163 us). Fix: stage P1[b]/P2[b] in LDS once per block
// (coalesced float4), then UNIFORM ds_read_b128 broadcasts (conflict-free,
// 4 floats/instr). float4 accumulator = 4 independent FMA chains.
__global__ __launch_bounds__(256) void pv_k(const float* __restrict__ P1g,
                                            const float* __restrict__ P2g,
                                            const u16* __restrict__ imgA,
                                            const u16* __restrict__ txtA,
                                            u16* __restrict__ gxw,
                                            u16* __restrict__ gyw) {
  __shared__ float ldsP1[36 * 64];
  __shared__ float ldsP2[50 * 64];
  const int b = blockIdx.x & 511;
  const int d = ((blockIdx.x >> 9) << 8) + threadIdx.x;
  const int tid = threadIdx.x;

  // stage P (coalesced float4 copies; pads [50..64) of P1 rows never read)
  {
    const float4* s1 = (const float4*)(P1g + (size_t)b * 2304);
    float4* l1 = (float4*)ldsP1;
    for (int i = tid; i < 576; i += 256) l1[i] = s1[i];
    const float4* s2 = (const float4*)(P2g + (size_t)b * 3200);
    float4* l2 = (float4*)ldsP2;
    for (int i = tid; i < 800; i += 256) l2[i] = s2[i];
  }

  const u16* tp = txtA + (size_t)b * 51200 + d;
  const u16* ip = imgA + (size_t)b * 36864 + d;
  float tv[50], iv[36];
#pragma unroll
  for (int m = 0; m < 50; ++m) tv[m] = b2f(tp[(size_t)m * 1024]);
#pragma unroll
  for (int n = 0; n < 36; ++n) iv[n] = b2f(ip[(size_t)n * 1024]);
  __syncthreads();

  u16* gx = gxw + (size_t)b * 36864 + d;
#pragma unroll
  for (int n = 0; n < 36; ++n) {
    const float4* pr4 = (const float4*)(ldsP1 + n * 64);
    float4 a4 = {0.f, 0.f, 0.f, 0.f};
#pragma unroll
    for (int i = 0; i < 12; ++i) {
      float4 p = pr4[i];
      a4.x = fmaf(p.x, tv[4 * i + 0], a4.x);
      a4.y = fmaf(p.y, tv[4 * i + 1], a4.y);
      a4.z = fmaf(p.z, tv[4 * i + 2], a4.z);
      a4.w = fmaf(p.w, tv[4 * i + 3], a4.w);
    }
    float acc = (a4.x + a4.y) + (a4.z + a4.w);
    acc = fmaf(ldsP1[n * 64 + 48], tv[48], acc);
    acc = fmaf(ldsP1[n * 64 + 49], tv[49], acc);
    float t = acc * iv[n];
    float g = acc / (1.f + __expf(-t));
    gx[(size_t)n * 1024] = f2b(g);
  }
  u16* gy = gyw + (size_t)b * 51200 + d;
#pragma unroll
  for (int m = 0; m < 50; ++m) {
    const float4* pr4 = (const float4*)(ldsP2 + m * 64);
    float4 a4 = {0.f, 0.f, 0.f, 0.f};
#pragma unroll
    for (int i = 0; i < 9; ++i) {
      float4 p = pr4[i];
      a4.x = fmaf(p.x, iv[4 * i + 0], a4.x);
      a4.y = fmaf(p.y, iv[4 * i + 1], a4.y);
      a4.z = fmaf(p.z, iv[4 * i + 2], a4.z);
      a4.w = fmaf(p.w, iv[4 * i + 3], a4.w);
    }
    float acc = (a4.x + a4.y) + (a4.z + a4.w);
    float t = acc * tv[m];
    float g = acc / (1.f + __expf(-t));
    gy[(size_t)m * 1024] = f2b(g);
  }
}

extern "C" void kernel_launch(void* const* d_in, const int* in_sizes, int n_in,
                              void* d_out, int out_size, void* d_ws, size_t ws_size,
                              hipStream_t stream) {
  (void)in_sizes; (void)n_in; (void)out_size; (void)ws_size;
  const float* imgE = (const float*)d_in[0];
  const float* txtE = (const float*)d_in[1];
  const void* xmask = d_in[2];
  const void* ymask = d_in[3];
  const float* W_img  = (const float*)d_in[4];
  const float* b_img  = (const float*)d_in[5];
  const float* W_txt  = (const float*)d_in[6];
  const float* b_txt  = (const float*)d_in[7];
  const float* W_img1 = (const float*)d_in[8];
  const float* b_img1 = (const float*)d_in[9];
  const float* W_txt1 = (const float*)d_in[10];
  const float* b_txt1 = (const float*)d_in[11];
  float* out_img = (float*)d_out;
  float* out_txt = out_img + (size_t)18874368;

  char* ws = (char*)d_ws;
  u16* Wt   = (u16*)(ws);                    // 4 x [1024][1024] bf16 (W^T)
  u16* imgA = (u16*)(ws + 8388608);          // [18432][1024] bf16
  u16* txtA = (u16*)(ws + 46137344);         // [25600][1024] bf16
  u16* Xb   = (u16*)(ws + 98566144);         // [18432][1024] bf16 (dies after score_k)
  u16* Yb   = (u16*)(ws + 136314880);        // [25600][1024] bf16 (dies after score_k)
  float* P1g = (float*)(ws + 188743680);     // [512][36][64] f32
  float* P2g = (float*)(ws + 193462272);     // [512][50][64] f32
  u16* gxw  = (u16*)(ws + 98566144);         // reuses Xb slot
  u16* gyw  = (u16*)(ws + 136314880);        // reuses Yb slot

  cast_k<<<2048, 256, 0, stream>>>((const float4*)imgE, imgA, 4718592);
  cast_k<<<2048, 256, 0, stream>>>((const float4*)txtE, txtA, 6553600);
  wtrans_k<<<dim3(32, 32, 4), 256, 0, stream>>>(W_img, W_txt, W_img1, W_txt1, Wt);
  gemm_k<0><<<dim3(8, 144), 256, 0, stream>>>(imgA, Wt,           b_img, nullptr, Xb, nullptr, 18432);
  gemm_k<0><<<dim3(8, 200), 256, 0, stream>>>(txtA, Wt + 1048576, b_txt, nullptr, Yb, nullptr, 25600);
  score_k<<<512, 512, 0, stream>>>(Xb, Yb, xmask, ymask, P1g, P2g);
  pv_k<<<2048, 256, 0, stream>>>(P1g, P2g, imgA, txtA, gxw, gyw);
  gemm_k<1><<<dim3(8, 144), 256, 0, stream>>>(gxw, Wt + 2097152, b_img1, imgE, nullptr, out_img, 18432);
  gemm_k<1><<<dim3(8, 200), 256, 0, stream>>>(gyw, Wt + 3145728, b_txt1, txtE, nullptr, out_txt, 25600);
}

// Round 6
// 425.921 us; speedup vs baseline: 1.6978x; 1.2534x over previous
//
#include <hip/hip_runtime.h>

typedef unsigned short u16;
typedef unsigned int u32;
typedef __attribute__((ext_vector_type(8))) short sv8;   // 8 x bf16 (4 VGPR)
typedef __attribute__((ext_vector_type(4))) float fv4;   // MFMA accumulator

__device__ __forceinline__ u16 f2b(float f) {
  u32 u = __builtin_bit_cast(u32, f);
  u32 r = (u + 0x7fffu + ((u >> 16) & 1u)) >> 16;
  return (u16)r;
}
__device__ __forceinline__ float b2f(u16 h) {
  return __builtin_bit_cast(float, ((u32)h) << 16);
}
__device__ __forceinline__ void gld16(const void* g, void* l) {
  __builtin_amdgcn_global_load_lds(
      (const __attribute__((address_space(1))) u32*)g,
      (__attribute__((address_space(3))) u32*)l, 16, 0, 0);
}

// ---------------- cast f32 -> bf16 ----------------
__global__ __launch_bounds__(256) void cast_k(const float4* __restrict__ in,
                                              u16* __restrict__ out, int n4) {
  int i = blockIdx.x * 256 + threadIdx.x;
  const int stride = gridDim.x * 256;
  for (; i < n4; i += stride) {
    float4 v = in[i];
    u32 p0 = (u32)f2b(v.x) | ((u32)f2b(v.y) << 16);
    u32 p1 = (u32)f2b(v.z) | ((u32)f2b(v.w) << 16);
    uint2 o; o.x = p0; o.y = p1;
    ((uint2*)out)[i] = o;
  }
}

// ---------------- weight transpose + cast:  Wt[e][d] = W[d][e] ----------------
__global__ __launch_bounds__(256) void wtrans_k(const float* __restrict__ W0,
                                                const float* __restrict__ W1,
                                                const float* __restrict__ W2,
                                                const float* __restrict__ W3,
                                                u16* __restrict__ out) {
  const int z = blockIdx.z;
  const float* W = (z == 0) ? W0 : (z == 1) ? W1 : (z == 2) ? W2 : W3;
  u16* o = out + (size_t)z * 1048576;
  __shared__ float t[32][33];
  const int tid = threadIdx.x;
  const int r = tid >> 5, cc = tid & 31;
  const int d0 = blockIdx.x * 32, e0 = blockIdx.y * 32;
#pragma unroll
  for (int i = 0; i < 4; ++i)
    t[r + i * 8][cc] = W[(size_t)(d0 + r + i * 8) * 1024 + e0 + cc];
  __syncthreads();
#pragma unroll
  for (int i = 0; i < 4; ++i) {
    int row = r + i * 8;
    o[(size_t)(e0 + row) * 1024 + d0 + cc] = f2b(t[cc][row]);
  }
}

// ---------------- merged 2-phase double-buffered GEMM ----------------
// C[row,1024] = A[row,1024] * Wt[1024,1024]^T for img (panels 0..143) and
// txt (panels 144..343) in ONE dispatch. BM=BN=128, BK=64, 4 waves.
// Pipeline: STAGE(t+1) issued BEFORE compute(t); counted vmcnt(8) + raw
// s_barrier (NOT __syncthreads: that drains vmcnt(0) and serializes - the
// R5 latency-bound 402 TF). LDS XOR-swizzle chunk^=(row&7) applied on the
// GLOBAL source (gld_lds dest must stay linear, m104/m173) and on ds_read.
// MODE 0: out = bf16(acc+bias); MODE 1: out = acc+bias+resid (f32).
template <int MODE>
__global__ __launch_bounds__(256, 2) void gemm2_k(
    const u16* __restrict__ Aimg, const u16* __restrict__ Atxt,
    const u16* __restrict__ Wimg, const u16* __restrict__ Wtxt,
    const float* __restrict__ bii, const float* __restrict__ btt,
    const float* __restrict__ rii, const float* __restrict__ rtt,
    u16* __restrict__ obi, u16* __restrict__ obt,
    float* __restrict__ ofi, float* __restrict__ oft) {
  __shared__ __attribute__((aligned(16))) char smem[65536];  // 2 x (A 16K | B 16K)
  const int tid = threadIdx.x;
  const int lane = tid & 63;
  const int w = tid >> 6;
  const int l15 = lane & 15, l4 = lane >> 4;
  const int lin = blockIdx.y * 8 + blockIdx.x;
  const int xcd = lin & 7, slot = lin >> 3;
  const int bcol0 = (slot & 7) * 128;
  const int prow = xcd + ((slot >> 3) << 3);     // 344 % 8 == 0 -> bijective

  const char* Ab; const char* Bb; const float* bias; const float* resid;
  u16* ob; float* of; int brow0;
  if (prow < 144) {
    brow0 = prow * 128;
    Ab = (const char*)Aimg + (size_t)brow0 * 2048;
    Bb = (const char*)Wimg + (size_t)bcol0 * 2048;
    bias = bii; resid = rii; ob = obi; of = ofi;
  } else {
    brow0 = (prow - 144) * 128;
    Ab = (const char*)Atxt + (size_t)brow0 * 2048;
    Bb = (const char*)Wtxt + (size_t)bcol0 * 2048;
    bias = btt; resid = rtt; ob = obt; of = oft;
  }
  const int wr = (w >> 1) * 64;
  const int wc = (w & 1) * 64;
  fv4 acc[4][4] = {};

  const int srow = tid >> 3;       // staging row within each 32-row group
  const int schunk = tid & 7;      // staging 16B-chunk within the 128B row

  auto STAGE = [&](int bb, int k0) {
#pragma unroll
    for (int i = 0; i < 4; ++i) {
      int row = i * 32 + srow;
      int g = schunk ^ (row & 7);                          // source pre-swizzle
      gld16(Ab + (size_t)row * 2048 + k0 * 2 + g * 16,
            smem + bb * 32768 + i * 4096 + tid * 16);      // linear LDS dest
    }
#pragma unroll
    for (int i = 0; i < 4; ++i) {
      int row = i * 32 + srow;
      int g = schunk ^ (row & 7);
      gld16(Bb + (size_t)row * 2048 + k0 * 2 + g * 16,
            smem + bb * 32768 + 16384 + i * 4096 + tid * 16);
    }
  };

  STAGE(0, 0);
  int cur = 0;
  for (int t = 0; t < 16; ++t) {
    if (t < 15) {
      STAGE(cur ^ 1, (t + 1) * 64);
      asm volatile("s_waitcnt vmcnt(8)" ::: "memory");   // tile t landed; t+1 in flight
    } else {
      asm volatile("s_waitcnt vmcnt(0)" ::: "memory");
    }
    __builtin_amdgcn_s_barrier();
    __builtin_amdgcn_sched_barrier(0);
    const char* Al = smem + cur * 32768;
    const char* Bl = Al + 16384;
#pragma unroll
    for (int ks = 0; ks < 2; ++ks) {
      sv8 af[4], bf[4];
#pragma unroll
      for (int m = 0; m < 4; ++m) {
        int row = wr + m * 16 + l15;
        int c = (ks * 4 + l4) ^ (row & 7);                 // read-side swizzle
        af[m] = *(const sv8*)(Al + row * 128 + c * 16);
      }
#pragma unroll
      for (int n = 0; n < 4; ++n) {
        int row = wc + n * 16 + l15;
        int c = (ks * 4 + l4) ^ (row & 7);
        bf[n] = *(const sv8*)(Bl + row * 128 + c * 16);
      }
#pragma unroll
      for (int m = 0; m < 4; ++m)
#pragma unroll
        for (int n = 0; n < 4; ++n)
          acc[m][n] = __builtin_amdgcn_mfma_f32_16x16x32_bf16(af[m], bf[n], acc[m][n], 0, 0, 0);
    }
    __builtin_amdgcn_sched_barrier(0);
    __builtin_amdgcn_s_barrier();                          // buf[cur] free to overwrite
    cur ^= 1;
  }

#pragma unroll
  for (int n = 0; n < 4; ++n) {
    const int col = bcol0 + wc + n * 16 + l15;
    const float bv = bias[col];
#pragma unroll
    for (int m = 0; m < 4; ++m) {
      fv4 v = acc[m][n];
#pragma unroll
      for (int j = 0; j < 4; ++j) {
        const int row = brow0 + wr + m * 16 + l4 * 4 + j;
        const size_t idx = (size_t)row * 1024 + col;
        float r = v[j] + bv;
        if (MODE == 0) ob[idx] = f2b(r);
        else           of[idx] = r + resid[idx];
      }
    }
  }
}

// ---------------- scores + masked softmax (one block per b) ----------------
__global__ __launch_bounds__(512) void score_k(const u16* __restrict__ Xb,
                                               const u16* __restrict__ Yb,
                                               const void* __restrict__ xmask,
                                               const void* __restrict__ ymask,
                                               float* __restrict__ P1g,
                                               float* __restrict__ P2g) {
  __shared__ float attL[48 * 65];        // stride 65 -> conflict-free col reads
  __shared__ float wxL[88];              // [0..35]=||x||, [36..85]=||y||
  __shared__ unsigned char msk[88];      // [0..35]=xm, [36..85]=ym
  const int b = blockIdx.x;
  const int tid = threadIdx.x;
  const int w = tid >> 6, lane = tid & 63;
  const int l15 = lane & 15, l4 = lane >> 4;

  // mask dtype auto-detect (int32 0/1 ORs to <=1; bytes OR to ~0x01010101)
  u32 det = 0;
  {
    const u32* mm = (const u32*)xmask;
#pragma unroll
    for (int i = 0; i < 16; ++i) det |= mm[i * 4];
    det |= mm[1] | mm[2] | mm[3];
  }
  const bool m_i32 = (det <= 1u);
  if (tid < 36)
    msk[tid] = (unsigned char)(m_i32 ? (((const int*)xmask)[b * 36 + tid] != 0)
                                     : (((const unsigned char*)xmask)[b * 36 + tid] != 0));
  if (tid >= 64 && tid < 114) {
    int m = tid - 64;
    msk[36 + m] = (unsigned char)(m_i32 ? (((const int*)ymask)[b * 50 + m] != 0)
                                        : (((const unsigned char*)ymask)[b * 50 + m] != 0));
  }

  const u16* Xr = Xb + (size_t)b * 36864;   // 36*1024
  const u16* Yr = Yb + (size_t)b * 51200;   // 50*1024

  if (w < 4) {
    // ---- row norms: 3 sweeps x (row = sweep*32 + tid>>3, part j = tid&7) ----
#pragma unroll
    for (int sweep = 0; sweep < 3; ++sweep) {
      int r = sweep * 32 + (tid >> 3);
      int j = tid & 7;
      if (r < 86) {
        const u32* p = (const u32*)((r < 36) ? (Xr + r * 1024)
                                             : (Yr + (size_t)(r - 36) * 1024)) + j * 64;
        float s = 0.f;
#pragma unroll
        for (int i = 0; i < 16; ++i) {
          uint4 q = ((const uint4*)p)[i];
          u32 qq[4] = {q.x, q.y, q.z, q.w};
#pragma unroll
          for (int k2 = 0; k2 < 4; ++k2) {
            float lo = __builtin_bit_cast(float, qq[k2] << 16);
            float hi = __builtin_bit_cast(float, qq[k2] & 0xffff0000u);
            s = fmaf(lo, lo, fmaf(hi, hi, s));
          }
        }
        s += __shfl_xor(s, 1); s += __shfl_xor(s, 2); s += __shfl_xor(s, 4);
        if (j == 0) wxL[r] = sqrtf(s);
      }
    }
  } else {
    // ---- scores: wave (w-4) owns col-tile tn; row-tiles tm=0..2 ----
    const int tn = w - 4;
    fv4 ac0 = {}, ac1 = {}, ac2 = {};
    const u16* Yp = Yr + (size_t)(tn * 16 + l15) * 1024 + l4 * 8;
    const u16* Xp = Xr + (size_t)l15 * 1024 + l4 * 8;
#pragma unroll 2
    for (int ks = 0; ks < 32; ++ks) {
      sv8 bf = *(const sv8*)(Yp + ks * 32);
      sv8 a0 = *(const sv8*)(Xp + ks * 32);
      sv8 a1 = *(const sv8*)(Xp + 16 * 1024 + ks * 32);
      sv8 a2 = *(const sv8*)(Xp + 32 * 1024 + ks * 32);
      ac0 = __builtin_amdgcn_mfma_f32_16x16x32_bf16(a0, bf, ac0, 0, 0, 0);
      ac1 = __builtin_amdgcn_mfma_f32_16x16x32_bf16(a1, bf, ac1, 0, 0, 0);
      ac2 = __builtin_amdgcn_mfma_f32_16x16x32_bf16(a2, bf, ac2, 0, 0, 0);
    }
    const int col = tn * 16 + l15;
#pragma unroll
    for (int j = 0; j < 4; ++j) {
      attL[(l4 * 4 + j) * 65 + col] = ac0[j];
      attL[(16 + l4 * 4 + j) * 65 + col] = ac1[j];
      attL[(32 + l4 * 4 + j) * 65 + col] = ac2[j];
    }
  }
  __syncthreads();

  // ---- parallel masked softmax: 2 sweeps of 64 rows, 8 lanes per row ----
#pragma unroll
  for (int sweep = 0; sweep < 2; ++sweep) {
    int R = sweep * 64 + (tid >> 3);
    int j = tid & 7;
    if (R < 36) {
      // img<-txt row n=R over m (masked by ym)
      float wxn = wxL[R];
      float sv[7];
#pragma unroll
      for (int i = 0; i < 7; ++i) {
        int m = j + i * 8;
        if (m < 50) {
          float den = fmaxf(wxn * wxL[36 + m], 1e-8f);
          float v = attL[R * 65 + m] / den;
          sv[i] = msk[36 + m] ? -1e9f : v;
        } else sv[i] = -3.4e38f;
      }
      float mx = sv[0];
#pragma unroll
      for (int i = 1; i < 7; ++i) mx = fmaxf(mx, sv[i]);
      mx = fmaxf(mx, __shfl_xor(mx, 1));
      mx = fmaxf(mx, __shfl_xor(mx, 2));
      mx = fmaxf(mx, __shfl_xor(mx, 4));
      float e[7], sum = 0.f;
#pragma unroll
      for (int i = 0; i < 7; ++i) {
        e[i] = (j + i * 8 < 50) ? __expf(sv[i] - mx) : 0.f;
        sum += e[i];
      }
      sum += __shfl_xor(sum, 1); sum += __shfl_xor(sum, 2); sum += __shfl_xor(sum, 4);
      float rs = 1.f / sum;
      float* dst = P1g + ((size_t)b * 36 + R) * 64;
#pragma unroll
      for (int i = 0; i < 7; ++i) {
        int m = j + i * 8;
        if (m < 50) dst[m] = e[i] * rs;
      }
    } else if (R < 86) {
      // txt<-img row m=R-36 over n (masked by xm)
      int m = R - 36;
      float wym = wxL[R];
      float sv[5];
#pragma unroll
      for (int i = 0; i < 5; ++i) {
        int n = j + i * 8;
        if (n < 36) {
          float den = fmaxf(wxL[n] * wym, 1e-8f);
          float v = attL[n * 65 + m] / den;
          sv[i] = msk[n] ? -1e9f : v;
        } else sv[i] = -3.4e38f;
      }
      float mx = sv[0];
#pragma unroll
      for (int i = 1; i < 5; ++i) mx = fmaxf(mx, sv[i]);
      mx = fmaxf(mx, __shfl_xor(mx, 1));
      mx = fmaxf(mx, __shfl_xor(mx, 2));
      mx = fmaxf(mx, __shfl_xor(mx, 4));
      float e[5], sum = 0.f;
#pragma unroll
      for (int i = 0; i < 5; ++i) {
        e[i] = (j + i * 8 < 36) ? __expf(sv[i] - mx) : 0.f;
        sum += e[i];
      }
      sum += __shfl_xor(sum, 1); sum += __shfl_xor(sum, 2); sum += __shfl_xor(sum, 4);
      float rs = 1.f / sum;
      float* dst = P2g + ((size_t)b * 50 + m) * 64;
#pragma unroll
      for (int i = 0; i < 5; ++i) {
        int n = j + i * 8;
        if (n < 36) dst[n] = e[i] * rs;
      }
    }
  }
}

// ---------------- P @ E + gate (thread = one d-column of one b) ----------------
__global__ __launch_bounds__(256) void pv_k(const float* __restrict__ P1g,
                                            const float* __restrict__ P2g,
                                            const u16* __restrict__ imgA,
                                            const u16* __restrict__ txtA,
                                            u16* __restrict__ gxw,
                                            u16* __restrict__ gyw) {
  __shared__ float ldsP1[36 * 64];
  __shared__ float ldsP2[50 * 64];
  const int b = blockIdx.x & 511;
  const int d = ((blockIdx.x >> 9) << 8) + threadIdx.x;
  const int tid = threadIdx.x;

  // stage P (coalesced float4 copies; pads [50..64) of P1 rows never read)
  {
    const float4* s1 = (const float4*)(P1g + (size_t)b * 2304);
    float4* l1 = (float4*)ldsP1;
    for (int i = tid; i < 576; i += 256) l1[i] = s1[i];
    const float4* s2 = (const float4*)(P2g + (size_t)b * 3200);
    float4* l2 = (float4*)ldsP2;
    for (int i = tid; i < 800; i += 256) l2[i] = s2[i];
  }

  const u16* tp = txtA + (size_t)b * 51200 + d;
  const u16* ip = imgA + (size_t)b * 36864 + d;
  float tv[50], iv[36];
#pragma unroll
  for (int m = 0; m < 50; ++m) tv[m] = b2f(tp[(size_t)m * 1024]);
#pragma unroll
  for (int n = 0; n < 36; ++n) iv[n] = b2f(ip[(size_t)n * 1024]);
  __syncthreads();

  u16* gx = gxw + (size_t)b * 36864 + d;
#pragma unroll
  for (int n = 0; n < 36; ++n) {
    const float4* pr4 = (const float4*)(ldsP1 + n * 64);
    float4 a4 = {0.f, 0.f, 0.f, 0.f};
#pragma unroll
    for (int i = 0; i < 12; ++i) {
      float4 p = pr4[i];
      a4.x = fmaf(p.x, tv[4 * i + 0], a4.x);
      a4.y = fmaf(p.y, tv[4 * i + 1], a4.y);
      a4.z = fmaf(p.z, tv[4 * i + 2], a4.z);
      a4.w = fmaf(p.w, tv[4 * i + 3], a4.w);
    }
    float acc = (a4.x + a4.y) + (a4.z + a4.w);
    acc = fmaf(ldsP1[n * 64 + 48], tv[48], acc);
    acc = fmaf(ldsP1[n * 64 + 49], tv[49], acc);
    float t = acc * iv[n];
    float g = acc / (1.f + __expf(-t));
    gx[(size_t)n * 1024] = f2b(g);
  }
  u16* gy = gyw + (size_t)b * 51200 + d;
#pragma unroll
  for (int m = 0; m < 50; ++m) {
    const float4* pr4 = (const float4*)(ldsP2 + m * 64);
    float4 a4 = {0.f, 0.f, 0.f, 0.f};
#pragma unroll
    for (int i = 0; i < 9; ++i) {
      float4 p = pr4[i];
      a4.x = fmaf(p.x, iv[4 * i + 0], a4.x);
      a4.y = fmaf(p.y, iv[4 * i + 1], a4.y);
      a4.z = fmaf(p.z, iv[4 * i + 2], a4.z);
      a4.w = fmaf(p.w, iv[4 * i + 3], a4.w);
    }
    float acc = (a4.x + a4.y) + (a4.z + a4.w);
    float t = acc * tv[m];
    float g = acc / (1.f + __expf(-t));
    gy[(size_t)m * 1024] = f2b(g);
  }
}

extern "C" void kernel_launch(void* const* d_in, const int* in_sizes, int n_in,
                              void* d_out, int out_size, void* d_ws, size_t ws_size,
                              hipStream_t stream) {
  (void)in_sizes; (void)n_in; (void)out_size; (void)ws_size;
  const float* imgE = (const float*)d_in[0];
  const float* txtE = (const float*)d_in[1];
  const void* xmask = d_in[2];
  const void* ymask = d_in[3];
  const float* W_img  = (const float*)d_in[4];
  const float* b_img  = (const float*)d_in[5];
  const float* W_txt  = (const float*)d_in[6];
  const float* b_txt  = (const float*)d_in[7];
  const float* W_img1 = (const float*)d_in[8];
  const float* b_img1 = (const float*)d_in[9];
  const float* W_txt1 = (const float*)d_in[10];
  const float* b_txt1 = (const float*)d_in[11];
  float* out_img = (float*)d_out;
  float* out_txt = out_img + (size_t)18874368;

  char* ws = (char*)d_ws;
  u16* Wt   = (u16*)(ws);                    // 4 x [1024][1024] bf16 (W^T)
  u16* imgA = (u16*)(ws + 8388608);          // [18432][1024] bf16
  u16* txtA = (u16*)(ws + 46137344);         // [25600][1024] bf16
  u16* Xb   = (u16*)(ws + 98566144);         // [18432][1024] bf16 (dies after score_k)
  u16* Yb   = (u16*)(ws + 136314880);        // [25600][1024] bf16 (dies after score_k)
  float* P1g = (float*)(ws + 188743680);     // [512][36][64] f32
  float* P2g = (float*)(ws + 193462272);     // [512][50][64] f32
  u16* gxw  = (u16*)(ws + 98566144);         // reuses Xb slot
  u16* gyw  = (u16*)(ws + 136314880);        // reuses Yb slot

  cast_k<<<2048, 256, 0, stream>>>((const float4*)imgE, imgA, 4718592);
  cast_k<<<2048, 256, 0, stream>>>((const float4*)txtE, txtA, 6553600);
  wtrans_k<<<dim3(32, 32, 4), 256, 0, stream>>>(W_img, W_txt, W_img1, W_txt1, Wt);
  gemm2_k<0><<<dim3(8, 344), 256, 0, stream>>>(
      imgA, txtA, Wt, Wt + 1048576, b_img, b_txt, nullptr, nullptr,
      Xb, Yb, nullptr, nullptr);
  score_k<<<512, 512, 0, stream>>>(Xb, Yb, xmask, ymask, P1g, P2g);
  pv_k<<<2048, 256, 0, stream>>>(P1g, P2g, imgA, txtA, gxw, gyw);
  gemm2_k<1><<<dim3(8, 344), 256, 0, stream>>>(
      gxw, gyw, Wt + 2097152, Wt + 3145728, b_img1, b_txt1, imgE, txtE,
      nullptr, nullptr, out_img, out_txt);
}